// Round 9
// baseline (1081.825 us; speedup 1.0000x reference)
//
#include <hip/hip_runtime.h>

typedef __attribute__((ext_vector_type(8))) short short8;   // 8 bf16
typedef __attribute__((ext_vector_type(4))) short short4v;  // 4 bf16
typedef __attribute__((ext_vector_type(4))) float f32x4;    // MFMA acc
typedef unsigned short ushort_t;
typedef unsigned int uint_t;

#define B_ 4
#define T_ 64
#define L_ 256
#define C_ 512
#define H_ 8
#define NTOK 65536   // B*T*L

// ---------- helpers ----------
__device__ __forceinline__ ushort_t f2bf(float f) {
    uint_t u = __float_as_uint(f);
    u += 0x7FFFu + ((u >> 16) & 1u);   // RNE
    return (ushort_t)(u >> 16);
}
__device__ __forceinline__ float bf2f(ushort_t u) {
    return __uint_as_float((uint_t)u << 16);
}
__device__ __forceinline__ uint_t pk2(float a, float b) {
    return (uint_t)f2bf(a) | ((uint_t)f2bf(b) << 16);
}

// ---------- RoPE tables: cos/sin[pos][i], pos<256, i<32 ----------
__global__ void rope_tables(float* __restrict__ cosT, float* __restrict__ sinT) {
    int idx = blockIdx.x * 256 + threadIdx.x;
    if (idx >= 256 * 32) return;
    int pos = idx >> 5, i = idx & 31;
    float theta = powf(10000.f, -(float)i * (1.f / 32.f));
    float ang = (float)pos * theta;
    float sv, cv;
    sincosf(ang, &sv, &cv);
    cosT[idx] = cv;
    sinT[idx] = sv;
}

// ---------- lnpack: per-token LN(x) -> bf16 row ----------
__global__ void lnpack(const float* __restrict__ xin, const float* __restrict__ lng,
                       const float* __restrict__ lnb, ushort_t* __restrict__ outb) {
    const int lane = threadIdx.x & 63;
    const int w = threadIdx.x >> 6;
    const size_t tok = (size_t)blockIdx.x * 4 + w;
    const float* row = xin + tok * 512 + lane * 8;
    float4 a = *(const float4*)row;
    float4 b = *(const float4*)(row + 4);
    float s = a.x + a.y + a.z + a.w + b.x + b.y + b.z + b.w;
    float q = a.x*a.x + a.y*a.y + a.z*a.z + a.w*a.w + b.x*b.x + b.y*b.y + b.z*b.z + b.w*b.w;
    #pragma unroll
    for (int off = 32; off >= 1; off >>= 1) {
        s += __shfl_xor(s, off);
        q += __shfl_xor(q, off);
    }
    const float m = s * (1.f / 512.f);
    const float v = q * (1.f / 512.f) - m * m;
    const float rs = 1.f / sqrtf(v + 1e-12f);
    float4 gv0 = *(const float4*)(lng + lane * 8);
    float4 gv1 = *(const float4*)(lng + lane * 8 + 4);
    float4 bv0 = *(const float4*)(lnb + lane * 8);
    float4 bv1 = *(const float4*)(lnb + lane * 8 + 4);
    float o0 = (a.x - m) * rs * gv0.x + bv0.x;
    float o1 = (a.y - m) * rs * gv0.y + bv0.y;
    float o2 = (a.z - m) * rs * gv0.z + bv0.z;
    float o3 = (a.w - m) * rs * gv0.w + bv0.w;
    float o4 = (b.x - m) * rs * gv1.x + bv1.x;
    float o5 = (b.y - m) * rs * gv1.y + bv1.y;
    float o6 = (b.z - m) * rs * gv1.z + bv1.z;
    float o7 = (b.w - m) * rs * gv1.w + bv1.w;
    uint4 pk = make_uint4(pk2(o0, o1), pk2(o2, o3), pk2(o4, o5), pk2(o6, o7));
    *(uint4*)(outb + tok * 512 + lane * 8) = pk;
}

// ---------- fold_w: Weff[1536][512] bf16 = [U.Wq*0.125 | U.Wk | V^T.Wv] ----------
// k_exp = U_h (W_k x) = (U_h W_k) x : fold the rank-16 expansion into weights
// so the expansion runs on the MFMA pipe (round-8 lesson: 2048 VALU FMA/thread
// in the attention kernel was the bottleneck).
__global__ void fold_w(const float* __restrict__ Wq, const float* __restrict__ Wk,
                       const float* __restrict__ Wv, const float* __restrict__ U,
                       const float* __restrict__ V, ushort_t* __restrict__ Weff) {
    const int o = blockIdx.x;               // 0..1535
    const int proj = o >> 9, orow = o & 511;
    const int h = orow >> 6, d = orow & 63;
    const float* W = (proj == 0) ? Wq : (proj == 1) ? Wk : Wv;
    float coef[16];
    #pragma unroll
    for (int r = 0; r < 16; ++r)
        coef[r] = (proj < 2) ? U[h * 1024 + d * 16 + r] : V[h * 1024 + r * 64 + d];
    const float scale = (proj == 0) ? 0.125f : 1.f;   // fold 1/sqrt(64) into q
    for (int c = threadIdx.x; c < 512; c += 256) {
        float acc = 0.f;
        #pragma unroll
        for (int r = 0; r < 16; ++r) acc += coef[r] * W[(h * 16 + r) * 512 + c];
        Weff[(long)o * 512 + c] = f2bf(acc * scale);
    }
}

// ---------- gemm_qkv3: qkve[M][1536] = Ab[M][512] @ Weff^T, rope in epilogue ----------
// 128x256 tile, 512 threads, A and B both bf16. Rope applies to cols<1024
// (q_exp, k_exp): pairs are adjacent cols = adjacent lanes -> one shfl_xor.
template<bool TIME>
__launch_bounds__(512)
__global__ void gemm_qkv3(const ushort_t* __restrict__ Ab, const ushort_t* __restrict__ Wb,
                          const float* __restrict__ cosT, const float* __restrict__ sinT,
                          ushort_t* __restrict__ Cout) {
    __shared__ ushort_t As[128][40];
    __shared__ ushort_t Bs[256][40];

    const int tid = threadIdx.x;
    const int ar = tid >> 2;          // 0..127
    const int ak = (tid & 3) << 3;    // 0,8,16,24
    const int br = tid >> 1;          // 0..255
    const int bk = (tid & 1) << 4;    // 0,16
    const int mBase = blockIdx.y * 128;
    const int nBase = blockIdx.x * 256;
    const long gm = mBase + ar;
    const long gn = nBase + br;

    f32x4 zero = {0.f, 0.f, 0.f, 0.f};
    f32x4 acc[4][4];
    #pragma unroll
    for (int a = 0; a < 4; ++a)
        #pragma unroll
        for (int b = 0; b < 4; ++b) acc[a][b] = zero;

    const int lane = tid & 63;
    const int wid = tid >> 6;
    const int wr = wid >> 2, wc = wid & 3;
    const int arw = wr * 64 + (lane & 15);
    const int brw = wc * 64 + (lane & 15);
    const int ko = (lane >> 4) << 3;

    for (int kt = 0; kt < 512; kt += 32) {
        const short8 av  = *(const short8*)(Ab + gm * 512 + kt + ak);
        const short8 bv0 = *(const short8*)(Wb + gn * 512 + kt + bk);
        const short8 bv1 = *(const short8*)(Wb + gn * 512 + kt + bk + 8);

        __syncthreads();
        *(short8*)&As[ar][ak] = av;
        *(short8*)&Bs[br][bk]     = bv0;
        *(short8*)&Bs[br][bk + 8] = bv1;
        __syncthreads();

        short8 af[4], bf[4];
        #pragma unroll
        for (int mi = 0; mi < 4; ++mi) af[mi] = *(const short8*)&As[arw + mi * 16][ko];
        #pragma unroll
        for (int ni = 0; ni < 4; ++ni) bf[ni] = *(const short8*)&Bs[brw + ni * 16][ko];
        #pragma unroll
        for (int mi = 0; mi < 4; ++mi)
            #pragma unroll
            for (int ni = 0; ni < 4; ++ni)
                acc[mi][ni] = __builtin_amdgcn_mfma_f32_16x16x32_bf16(af[mi], bf[ni], acc[mi][ni], 0, 0, 0);
    }

    const int l15 = lane & 15;
    #pragma unroll
    for (int mi = 0; mi < 4; ++mi) {
        #pragma unroll
        for (int ni = 0; ni < 4; ++ni) {
            const int col = nBase + wc * 64 + ni * 16 + l15;
            const int dd = col & 63;
            const int i = dd >> 1;
            #pragma unroll
            for (int jj = 0; jj < 4; ++jj) {
                const long row = mBase + wr * 64 + mi * 16 + ((lane >> 4) << 2) + jj;
                float v = acc[mi][ni][jj];
                const float other = __shfl_xor(v, 1);
                if (col < 1024) {   // rope q_exp and k_exp
                    const int pos = TIME ? ((int)(row >> 8) & 63) : ((int)row & 255);
                    const float c = cosT[pos * 32 + i], s = sinT[pos * 32 + i];
                    v = (l15 & 1) ? (other * s + v * c) : (v * c - other * s);
                }
                Cout[row * 1536 + col] = f2bf(v);
            }
        }
    }
}

// ---------- gemm256: 128x256-tile GEMM (gate / proj paths), unchanged ----------
template<int EPI, bool CA>
__launch_bounds__(512)
__global__ void gemm256(const float* __restrict__ A1f, const ushort_t* __restrict__ A1b,
                        const ushort_t* __restrict__ A2b, const float* __restrict__ Bw,
                        float* __restrict__ Cout, const float* __restrict__ bias,
                        const float* __restrict__ R1, const ushort_t* __restrict__ R2b) {
    constexpr int K = CA ? 1024 : 512;
    __shared__ ushort_t As[128][40];
    __shared__ ushort_t Bs[256][40];

    const int tid = threadIdx.x;
    const int ar = tid >> 2;
    const int ak = (tid & 3) << 3;
    const int br = tid >> 1;
    const int bk = (tid & 1) << 4;
    const int mBase = blockIdx.y * 128;
    const int nBase = blockIdx.x * 256;
    const long gm = mBase + ar;
    const long gn = nBase + br;

    f32x4 zero = {0.f, 0.f, 0.f, 0.f};
    f32x4 acc[4][4];
    #pragma unroll
    for (int a = 0; a < 4; ++a)
        #pragma unroll
        for (int b = 0; b < 4; ++b) acc[a][b] = zero;

    const int lane = tid & 63;
    const int wid = tid >> 6;
    const int wr = wid >> 2, wc = wid & 3;
    const int arw = wr * 64 + (lane & 15);
    const int brw = wc * 64 + (lane & 15);
    const int ko = (lane >> 4) << 3;

    for (int kt = 0; kt < K; kt += 32) {
        const int kb = kt + ak;
        short8 av;
        if (CA) {
            if (kb < 512) {
                const float* ap = A1f + gm * 512 + kb;
                float4 x0 = *(const float4*)(ap);
                float4 x1 = *(const float4*)(ap + 4);
                uint4 p = make_uint4(pk2(x0.x, x0.y), pk2(x0.z, x0.w),
                                     pk2(x1.x, x1.y), pk2(x1.z, x1.w));
                av = *(short8*)&p;
            } else {
                av = *(const short8*)(A2b + gm * 512 + (kb - 512));
            }
        } else {
            av = *(const short8*)(A1b + gm * 512 + kb);
        }
        const float* bp = Bw + gn * (long)K + kt + bk;
        float4 w0 = *(const float4*)(bp);
        float4 w1 = *(const float4*)(bp + 4);
        float4 w2 = *(const float4*)(bp + 8);
        float4 w3 = *(const float4*)(bp + 12);

        __syncthreads();
        *(short8*)&As[ar][ak] = av;
        uint4 pb0 = make_uint4(pk2(w0.x, w0.y), pk2(w0.z, w0.w), pk2(w1.x, w1.y), pk2(w1.z, w1.w));
        uint4 pb1 = make_uint4(pk2(w2.x, w2.y), pk2(w2.z, w2.w), pk2(w3.x, w3.y), pk2(w3.z, w3.w));
        *(uint4*)&Bs[br][bk]     = pb0;
        *(uint4*)&Bs[br][bk + 8] = pb1;
        __syncthreads();

        short8 af[4], bf[4];
        #pragma unroll
        for (int mi = 0; mi < 4; ++mi) af[mi] = *(const short8*)&As[arw + mi * 16][ko];
        #pragma unroll
        for (int ni = 0; ni < 4; ++ni) bf[ni] = *(const short8*)&Bs[brw + ni * 16][ko];
        #pragma unroll
        for (int mi = 0; mi < 4; ++mi)
            #pragma unroll
            for (int ni = 0; ni < 4; ++ni)
                acc[mi][ni] = __builtin_amdgcn_mfma_f32_16x16x32_bf16(af[mi], bf[ni], acc[mi][ni], 0, 0, 0);
    }

    #pragma unroll
    for (int mi = 0; mi < 4; ++mi) {
        #pragma unroll
        for (int ni = 0; ni < 4; ++ni) {
            #pragma unroll
            for (int jj = 0; jj < 4; ++jj) {
                const long row = mBase + wr * 64 + mi * 16 + ((lane >> 4) << 2) + jj;
                const long col = nBase + wc * 64 + ni * 16 + (lane & 15);
                const long idx = row * 512 + col;
                float v = acc[mi][ni][jj];
                if (EPI == 1) {
                    float z = v + bias[col];
                    float g = 1.f / (1.f + __expf(-z));
                    Cout[idx] = g * R1[idx] + (1.f - g) * bf2f(R2b[idx]);
                } else {
                    Cout[idx] = v + bias[col] + R1[idx];
                }
            }
        }
    }
}

// ---------- attn3: pure flash MFMA attention on precomputed q/k/v_exp ----------
// qkve[tok][1536] bf16 = q_exp|k_exp|v_exp (roped+scaled in GEMM epilogue).
// Staging is a straight copy: K -> XOR-swizzled LDS, V -> transposed LDS;
// Q fragments load directly as short8. Flash chunks of 64 keys; no
// max-tracking (scores tiny; exp(min(s,30)) clamp) — validated round 8.
template<int SEQ, bool TIME>
__launch_bounds__(256)
__global__ void attn3(const ushort_t* __restrict__ qkve, ushort_t* __restrict__ xattn) {
    constexpr int NCH = SEQ / 64;     // key chunks
    constexpr int NQT = SEQ / 64;     // q-tiles per wave
    constexpr int NPART = 256 / SEQ;  // threads sharing one key row
    constexpr int DCH = 8 / NPART;    // 8-elem chunks per thread in staging

    __shared__ short Klds[SEQ][64];   // swizzled: chunk ^= (key&7)
    __shared__ short VTs[64][SEQ];    // V^T[d][key], swizzled
    __shared__ short Pw[4][16][40];   // per-wave P window

    const int bx = blockIdx.x;
    const int h = bx & 7;
    const int grp = bx >> 3;
    int tokBase, tokStride;
    if (TIME) {
        const int l = grp & (L_ - 1);
        const int b = grp >> 8;
        tokBase = b * T_ * L_ + l;
        tokStride = L_;
    } else {
        tokBase = grp * L_;
        tokStride = 1;
    }
    const int tid = threadIdx.x;
    const int lane = tid & 63;
    const int w = tid >> 6;

    // ---- stage K (swizzled) and V (transposed+swizzled) ----
    {
        const int key = tid & (SEQ - 1);
        const int part = tid / SEQ;
        const long tok = tokBase + (long)key * tokStride;
        const ushort_t* kb = qkve + tok * 1536 + 512 + h * 64;
        const ushort_t* vb = qkve + tok * 1536 + 1024 + h * 64;
        #pragma unroll
        for (int c = 0; c < DCH; ++c) {
            const int chunk = part * DCH + c;
            const short8 kv = *(const short8*)(kb + chunk * 8);
            *(short8*)&Klds[key][(chunk ^ (key & 7)) * 8] = kv;
            const short8 vv = *(const short8*)(vb + chunk * 8);
            #pragma unroll
            for (int j = 0; j < 8; ++j) {
                const int d = chunk * 8 + j;
                VTs[d][(((key >> 3) ^ (d & 7)) * 8) + (key & 7)] = vv[j];
            }
        }
    }
    __syncthreads();

    const int l15 = lane & 15;
    const int g = lane >> 4;

    #pragma unroll 1
    for (int qt = 0; qt < NQT; ++qt) {
        const int qbase = qt * 64 + w * 16;
        const long qtok = tokBase + (long)(qbase + l15) * tokStride;

        // ---- Q fragments: direct bf16 loads (already roped+scaled) ----
        const ushort_t* qb = qkve + qtok * 1536 + h * 64;
        const short8 Qf0 = *(const short8*)(qb + g * 8);
        const short8 Qf1 = *(const short8*)(qb + 32 + g * 8);

        f32x4 O[4];
        #pragma unroll
        for (int nj = 0; nj < 4; ++nj) { f32x4 z = {0.f,0.f,0.f,0.f}; O[nj] = z; }
        float psum = 0.f;

        #pragma unroll 1
        for (int kb2 = 0; kb2 < NCH; ++kb2) {
            // S^T chunk = mfma(K, Q): lane holds P[key=kb2*64+16f4+4g+jj][q=l15]
            f32x4 S[4];
            #pragma unroll
            for (int f4 = 0; f4 < 4; ++f4) {
                const int row = kb2 * 64 + f4 * 16 + l15;
                const short8 a0 = *(const short8*)&Klds[row][((0 + g) ^ (l15 & 7)) * 8];
                const short8 a1 = *(const short8*)&Klds[row][((4 + g) ^ (l15 & 7)) * 8];
                f32x4 z = {0.f, 0.f, 0.f, 0.f};
                z = __builtin_amdgcn_mfma_f32_16x16x32_bf16(a0, Qf0, z, 0, 0, 0);
                S[f4] = __builtin_amdgcn_mfma_f32_16x16x32_bf16(a1, Qf1, z, 0, 0, 0);
            }
            #pragma unroll
            for (int f4 = 0; f4 < 4; ++f4)
                #pragma unroll
                for (int jj = 0; jj < 4; ++jj) {
                    const float p = __expf(fminf(S[f4][jj], 30.f));
                    S[f4][jj] = p;
                    psum += p;
                }

            // PV: 2 k-steps of 32 keys via wave-private Pw window
            #pragma unroll
            for (int sl = 0; sl < 2; ++sl) {
                #pragma unroll
                for (int h2 = 0; h2 < 2; ++h2) {
                    const int f4 = 2 * sl + h2;
                    short4v pv;
                    pv[0] = (short)f2bf(S[f4][0]);
                    pv[1] = (short)f2bf(S[f4][1]);
                    pv[2] = (short)f2bf(S[f4][2]);
                    pv[3] = (short)f2bf(S[f4][3]);
                    *(short4v*)&Pw[w][l15][h2 * 16 + 4 * g] = pv;
                }
                const short8 pa = *(const short8*)&Pw[w][l15][8 * g];
                const int sg = kb2 * 2 + sl;
                #pragma unroll
                for (int nj = 0; nj < 4; ++nj) {
                    const int row = nj * 16 + l15;
                    const short8 bv = *(const short8*)&VTs[row][((4 * sg + g) ^ (l15 & 7)) * 8];
                    O[nj] = __builtin_amdgcn_mfma_f32_16x16x32_bf16(pa, bv, O[nj], 0, 0, 0);
                }
            }
        }

        // ---- final normalize + store bf16 ----
        psum += __shfl_xor(psum, 16);
        psum += __shfl_xor(psum, 32);
        const float inv = 1.f / psum;
        #pragma unroll
        for (int jj = 0; jj < 4; ++jj) {
            const float invq = __shfl(inv, 4 * g + jj);
            const long row = tokBase + (long)(qbase + 4 * g + jj) * tokStride;
            ushort_t* op = xattn + row * 512 + h * 64 + l15;
            #pragma unroll
            for (int nj = 0; nj < 4; ++nj)
                op[nj * 16] = f2bf(O[nj][jj] * invq);
        }
    }
}

// ---------- launch ----------
extern "C" void kernel_launch(void* const* d_in, const int* in_sizes, int n_in,
                              void* d_out, int out_size, void* d_ws, size_t ws_size,
                              hipStream_t stream) {
    const float* x      = (const float*)d_in[0];
    const float* t_Wq   = (const float*)d_in[3];
    const float* t_Wk   = (const float*)d_in[4];
    const float* t_Wv   = (const float*)d_in[5];
    const float* t_U    = (const float*)d_in[6];
    const float* t_V    = (const float*)d_in[7];
    const float* a_Wq   = (const float*)d_in[8];
    const float* a_Wk   = (const float*)d_in[9];
    const float* a_Wv   = (const float*)d_in[10];
    const float* a_U    = (const float*)d_in[11];
    const float* a_V    = (const float*)d_in[12];
    const float* ln1_g  = (const float*)d_in[13];
    const float* ln1_b  = (const float*)d_in[14];
    const float* ln2_g  = (const float*)d_in[15];
    const float* ln2_b  = (const float*)d_in[16];
    const float* ln3_g  = (const float*)d_in[17];
    const float* ln3_b  = (const float*)d_in[18];
    const float* proj_W = (const float*)d_in[19];
    const float* proj_b = (const float*)d_in[20];
    const float* gt_W   = (const float*)d_in[21];
    const float* gt_b   = (const float*)d_in[22];
    const float* ga_W   = (const float*)d_in[23];
    const float* ga_b   = (const float*)d_in[24];
    float* out = (float*)d_out;

    const size_t NC = (size_t)NTOK * 512;
    float* hbuf = (float*)d_ws;                        // phase-A gate out (fp32, 128MB)
    ushort_t* lnb  = (ushort_t*)(hbuf + NC);           // LN out bf16, reused as xatt (64MB)
    ushort_t* qkve = lnb + NC;                         // q/k/v_exp bf16 [NTOK][1536] (192MB)
    float* gout = (float*)qkve;                        // phase-B gate out ALIASES qkve
                                                       // (qkve dead after attn3 B; gate B
                                                       //  reads only hbuf/lnb — no overlap)
    ushort_t* Weff = qkve + (size_t)NTOK * 1536;       // folded weights bf16 (1.5MB)
    float* cosT = (float*)(Weff + 1536 * 512);
    float* sinT = cosT + 8192;
    ushort_t* xattb = lnb;

    rope_tables<<<32, 256, 0, stream>>>(cosT, sinT);

    // ===== Phase A: time attention (seq=T, batch=B*L) =====
    fold_w<<<1536, 256, 0, stream>>>(t_Wq, t_Wk, t_Wv, t_U, t_V, Weff);
    lnpack<<<NTOK / 4, 256, 0, stream>>>(x, ln1_g, ln1_b, lnb);
    gemm_qkv3<true><<<dim3(6, 512), 512, 0, stream>>>(lnb, Weff, cosT, sinT, qkve);
    attn3<64, true><<<B_ * L_ * H_, 256, 0, stream>>>(qkve, xattb);
    gemm256<1, true><<<dim3(2, 512), 512, 0, stream>>>(x, nullptr, xattb, gt_W, hbuf, gt_b, x, xattb);

    // ===== Phase B: amino-acid attention (seq=L, batch=B*T) =====
    fold_w<<<1536, 256, 0, stream>>>(a_Wq, a_Wk, a_Wv, a_U, a_V, Weff);
    lnpack<<<NTOK / 4, 256, 0, stream>>>(hbuf, ln2_g, ln2_b, lnb);
    gemm_qkv3<false><<<dim3(6, 512), 512, 0, stream>>>(lnb, Weff, cosT, sinT, qkve);
    attn3<256, false><<<B_ * T_ * H_, 256, 0, stream>>>(qkve, xattb);
    gemm256<1, true><<<dim3(2, 512), 512, 0, stream>>>(hbuf, nullptr, xattb, ga_W, gout, ga_b, hbuf, xattb);

    // ===== Phase C: output projection + residual =====
    lnpack<<<NTOK / 4, 256, 0, stream>>>(gout, ln3_g, ln3_b, lnb);
    gemm256<2, false><<<dim3(2, 512), 512, 0, stream>>>(nullptr, lnb, nullptr, proj_W, out, proj_b, gout, nullptr);
}

// Round 10
// 1063.960 us; speedup vs baseline: 1.0168x; 1.0168x over previous
//
#include <hip/hip_runtime.h>

typedef __attribute__((ext_vector_type(8))) short short8;   // 8 bf16
typedef __attribute__((ext_vector_type(4))) short short4v;  // 4 bf16
typedef __attribute__((ext_vector_type(4))) float f32x4;    // MFMA acc
typedef unsigned short ushort_t;
typedef unsigned int uint_t;

#define B_ 4
#define T_ 64
#define L_ 256
#define C_ 512
#define H_ 8
#define NTOK 65536   // B*T*L

// ---------- helpers ----------
__device__ __forceinline__ ushort_t f2bf(float f) {
    uint_t u = __float_as_uint(f);
    u += 0x7FFFu + ((u >> 16) & 1u);   // RNE
    return (ushort_t)(u >> 16);
}
__device__ __forceinline__ float bf2f(ushort_t u) {
    return __uint_as_float((uint_t)u << 16);
}
__device__ __forceinline__ uint_t pk2(float a, float b) {
    return (uint_t)f2bf(a) | ((uint_t)f2bf(b) << 16);
}

// ---------- RoPE tables: cos/sin[pos][i], pos<256, i<32 ----------
__global__ void rope_tables(float* __restrict__ cosT, float* __restrict__ sinT) {
    int idx = blockIdx.x * 256 + threadIdx.x;
    if (idx >= 256 * 32) return;
    int pos = idx >> 5, i = idx & 31;
    float theta = powf(10000.f, -(float)i * (1.f / 32.f));
    float ang = (float)pos * theta;
    float sv, cv;
    sincosf(ang, &sv, &cv);
    cosT[idx] = cv;
    sinT[idx] = sv;
}

// ---------- lnpack: per-token LN(x) -> bf16 row ----------
__global__ void lnpack(const float* __restrict__ xin, const float* __restrict__ lng,
                       const float* __restrict__ lnb, ushort_t* __restrict__ outb) {
    const int lane = threadIdx.x & 63;
    const int w = threadIdx.x >> 6;
    const size_t tok = (size_t)blockIdx.x * 4 + w;
    const float* row = xin + tok * 512 + lane * 8;
    float4 a = *(const float4*)row;
    float4 b = *(const float4*)(row + 4);
    float s = a.x + a.y + a.z + a.w + b.x + b.y + b.z + b.w;
    float q = a.x*a.x + a.y*a.y + a.z*a.z + a.w*a.w + b.x*b.x + b.y*b.y + b.z*b.z + b.w*b.w;
    #pragma unroll
    for (int off = 32; off >= 1; off >>= 1) {
        s += __shfl_xor(s, off);
        q += __shfl_xor(q, off);
    }
    const float m = s * (1.f / 512.f);
    const float v = q * (1.f / 512.f) - m * m;
    const float rs = 1.f / sqrtf(v + 1e-12f);
    float4 gv0 = *(const float4*)(lng + lane * 8);
    float4 gv1 = *(const float4*)(lng + lane * 8 + 4);
    float4 bv0 = *(const float4*)(lnb + lane * 8);
    float4 bv1 = *(const float4*)(lnb + lane * 8 + 4);
    float o0 = (a.x - m) * rs * gv0.x + bv0.x;
    float o1 = (a.y - m) * rs * gv0.y + bv0.y;
    float o2 = (a.z - m) * rs * gv0.z + bv0.z;
    float o3 = (a.w - m) * rs * gv0.w + bv0.w;
    float o4 = (b.x - m) * rs * gv1.x + bv1.x;
    float o5 = (b.y - m) * rs * gv1.y + bv1.y;
    float o6 = (b.z - m) * rs * gv1.z + bv1.z;
    float o7 = (b.w - m) * rs * gv1.w + bv1.w;
    uint4 pk = make_uint4(pk2(o0, o1), pk2(o2, o3), pk2(o4, o5), pk2(o6, o7));
    *(uint4*)(outb + tok * 512 + lane * 8) = pk;
}

// ---------- fold_w: Weff[1536][512] bf16 = [U.Wq*0.125 | U.Wk | V^T.Wv] ----------
__global__ void fold_w(const float* __restrict__ Wq, const float* __restrict__ Wk,
                       const float* __restrict__ Wv, const float* __restrict__ U,
                       const float* __restrict__ V, ushort_t* __restrict__ Weff) {
    const int o = blockIdx.x;               // 0..1535
    const int proj = o >> 9, orow = o & 511;
    const int h = orow >> 6, d = orow & 63;
    const float* W = (proj == 0) ? Wq : (proj == 1) ? Wk : Wv;
    float coef[16];
    #pragma unroll
    for (int r = 0; r < 16; ++r)
        coef[r] = (proj < 2) ? U[h * 1024 + d * 16 + r] : V[h * 1024 + r * 64 + d];
    const float scale = (proj == 0) ? 0.125f : 1.f;   // fold 1/sqrt(64) into q
    for (int c = threadIdx.x; c < 512; c += 256) {
        float acc = 0.f;
        #pragma unroll
        for (int r = 0; r < 16; ++r) acc += coef[r] * W[(h * 16 + r) * 512 + c];
        Weff[(long)o * 512 + c] = f2bf(acc * scale);
    }
}

// ---------- gemm_qkv3: qkve[M][1536] = Ab[M][512] @ Weff^T ----------
// 128x256 tile, 512 threads, A and B both bf16. 1D grid with XCD swizzle:
// a row-panel's 6 column-blocks run consecutively on ONE XCD so the A-panel
// stays in that XCD's L2 (round-9 lesson: round-robin spread A across 6 L2s,
// tripling HBM fetch). Epilogue stages bf16 C through LDS per 64-col slice:
// rope pairs become in-lane (zero shuffles), stores become 16B coalesced
// (round-9 lesson: 2-byte scattered stores + 64 shfl/thread bound the kernel).
template<bool TIME>
__launch_bounds__(512)
__global__ void gemm_qkv3(const ushort_t* __restrict__ Ab, const ushort_t* __restrict__ Wb,
                          const float* __restrict__ cosT, const float* __restrict__ sinT,
                          ushort_t* __restrict__ Cout) {
    __shared__ ushort_t As[128][40];
    __shared__ ushort_t Bs[256][40];
    __shared__ ushort_t Ebuf[128][72];    // epilogue slice buffer (pad 8)

    // XCD-aware swizzle: id%8 = XCD (dispatch round-robin); each XCD owns 64
    // row panels; a panel's 6 col-blocks are consecutive within the XCD.
    const int id = blockIdx.x;            // 0..3071
    const int xcd = id & 7;
    const int j = id >> 3;                // 0..383
    const int mBase = (xcd * 64 + j / 6) * 128;
    const int nBase = (j % 6) * 256;

    const int tid = threadIdx.x;
    const int ar = tid >> 2;          // 0..127
    const int ak = (tid & 3) << 3;    // 0,8,16,24
    const int br = tid >> 1;          // 0..255
    const int bk = (tid & 1) << 4;    // 0,16
    const long gm = mBase + ar;
    const long gn = nBase + br;

    f32x4 zero = {0.f, 0.f, 0.f, 0.f};
    f32x4 acc[4][4];
    #pragma unroll
    for (int a = 0; a < 4; ++a)
        #pragma unroll
        for (int b = 0; b < 4; ++b) acc[a][b] = zero;

    const int lane = tid & 63;
    const int wid = tid >> 6;
    const int wr = wid >> 2, wc = wid & 3;
    const int arw = wr * 64 + (lane & 15);
    const int brw = wc * 64 + (lane & 15);
    const int ko = (lane >> 4) << 3;
    const int l15 = lane & 15;
    const int g = lane >> 4;

    for (int kt = 0; kt < 512; kt += 32) {
        const short8 av  = *(const short8*)(Ab + gm * 512 + kt + ak);
        const short8 bv0 = *(const short8*)(Wb + gn * 512 + kt + bk);
        const short8 bv1 = *(const short8*)(Wb + gn * 512 + kt + bk + 8);

        __syncthreads();
        *(short8*)&As[ar][ak] = av;
        *(short8*)&Bs[br][bk]     = bv0;
        *(short8*)&Bs[br][bk + 8] = bv1;
        __syncthreads();

        short8 af[4], bf[4];
        #pragma unroll
        for (int mi = 0; mi < 4; ++mi) af[mi] = *(const short8*)&As[arw + mi * 16][ko];
        #pragma unroll
        for (int ni = 0; ni < 4; ++ni) bf[ni] = *(const short8*)&Bs[brw + ni * 16][ko];
        #pragma unroll
        for (int mi = 0; mi < 4; ++mi)
            #pragma unroll
            for (int ni = 0; ni < 4; ++ni)
                acc[mi][ni] = __builtin_amdgcn_mfma_f32_16x16x32_bf16(af[mi], bf[ni], acc[mi][ni], 0, 0, 0);
    }

    // ---- epilogue: 4 stages of 64-col slices through Ebuf ----
    #pragma unroll 1
    for (int s = 0; s < 4; ++s) {
        __syncthreads();   // prev stage reads done (and k-loop LDS reads on s=0)
        if (wc == s) {
            #pragma unroll
            for (int mi = 0; mi < 4; ++mi)
                #pragma unroll
                for (int ni = 0; ni < 4; ++ni)
                    #pragma unroll
                    for (int jj = 0; jj < 4; ++jj)
                        Ebuf[wr * 64 + mi * 16 + g * 4 + jj][ni * 16 + l15] =
                            f2bf(acc[mi][ni][jj]);
        }
        __syncthreads();
        #pragma unroll
        for (int it = 0; it < 2; ++it) {
            const int u = tid + it * 512;
            const int row = u >> 3, c8 = u & 7;
            short8 v8 = *(const short8*)&Ebuf[row][c8 * 8];
            const long grow = mBase + row;
            const int gcol = nBase + s * 64 + c8 * 8;
            ushort_t* dst = Cout + grow * 1536 + gcol;
            if (gcol < 1024) {   // rope q_exp / k_exp: pairs are in-lane
                const int pos = TIME ? ((int)(grow >> 8) & 63) : ((int)grow & 255);
                const float* cT = cosT + pos * 32 + c8 * 4;
                const float* sT = sinT + pos * 32 + c8 * 4;
                uint_t pkv[4];
                #pragma unroll
                for (int p = 0; p < 4; ++p) {
                    const float cc = cT[p], ss = sT[p];
                    const float re = bf2f((ushort_t)v8[2 * p]);
                    const float im = bf2f((ushort_t)v8[2 * p + 1]);
                    pkv[p] = pk2(re * cc - im * ss, re * ss + im * cc);
                }
                *(uint4*)dst = make_uint4(pkv[0], pkv[1], pkv[2], pkv[3]);
            } else {             // v_exp: straight copy
                *(short8*)dst = v8;
            }
        }
    }
}

// ---------- gemm256: 128x256-tile GEMM (gate / proj paths), unchanged ----------
template<int EPI, bool CA>
__launch_bounds__(512)
__global__ void gemm256(const float* __restrict__ A1f, const ushort_t* __restrict__ A1b,
                        const ushort_t* __restrict__ A2b, const float* __restrict__ Bw,
                        float* __restrict__ Cout, const float* __restrict__ bias,
                        const float* __restrict__ R1, const ushort_t* __restrict__ R2b) {
    constexpr int K = CA ? 1024 : 512;
    __shared__ ushort_t As[128][40];
    __shared__ ushort_t Bs[256][40];

    const int tid = threadIdx.x;
    const int ar = tid >> 2;
    const int ak = (tid & 3) << 3;
    const int br = tid >> 1;
    const int bk = (tid & 1) << 4;
    const int mBase = blockIdx.y * 128;
    const int nBase = blockIdx.x * 256;
    const long gm = mBase + ar;
    const long gn = nBase + br;

    f32x4 zero = {0.f, 0.f, 0.f, 0.f};
    f32x4 acc[4][4];
    #pragma unroll
    for (int a = 0; a < 4; ++a)
        #pragma unroll
        for (int b = 0; b < 4; ++b) acc[a][b] = zero;

    const int lane = tid & 63;
    const int wid = tid >> 6;
    const int wr = wid >> 2, wc = wid & 3;
    const int arw = wr * 64 + (lane & 15);
    const int brw = wc * 64 + (lane & 15);
    const int ko = (lane >> 4) << 3;

    for (int kt = 0; kt < K; kt += 32) {
        const int kb = kt + ak;
        short8 av;
        if (CA) {
            if (kb < 512) {
                const float* ap = A1f + gm * 512 + kb;
                float4 x0 = *(const float4*)(ap);
                float4 x1 = *(const float4*)(ap + 4);
                uint4 p = make_uint4(pk2(x0.x, x0.y), pk2(x0.z, x0.w),
                                     pk2(x1.x, x1.y), pk2(x1.z, x1.w));
                av = *(short8*)&p;
            } else {
                av = *(const short8*)(A2b + gm * 512 + (kb - 512));
            }
        } else {
            av = *(const short8*)(A1b + gm * 512 + kb);
        }
        const float* bp = Bw + gn * (long)K + kt + bk;
        float4 w0 = *(const float4*)(bp);
        float4 w1 = *(const float4*)(bp + 4);
        float4 w2 = *(const float4*)(bp + 8);
        float4 w3 = *(const float4*)(bp + 12);

        __syncthreads();
        *(short8*)&As[ar][ak] = av;
        uint4 pb0 = make_uint4(pk2(w0.x, w0.y), pk2(w0.z, w0.w), pk2(w1.x, w1.y), pk2(w1.z, w1.w));
        uint4 pb1 = make_uint4(pk2(w2.x, w2.y), pk2(w2.z, w2.w), pk2(w3.x, w3.y), pk2(w3.z, w3.w));
        *(uint4*)&Bs[br][bk]     = pb0;
        *(uint4*)&Bs[br][bk + 8] = pb1;
        __syncthreads();

        short8 af[4], bf[4];
        #pragma unroll
        for (int mi = 0; mi < 4; ++mi) af[mi] = *(const short8*)&As[arw + mi * 16][ko];
        #pragma unroll
        for (int ni = 0; ni < 4; ++ni) bf[ni] = *(const short8*)&Bs[brw + ni * 16][ko];
        #pragma unroll
        for (int mi = 0; mi < 4; ++mi)
            #pragma unroll
            for (int ni = 0; ni < 4; ++ni)
                acc[mi][ni] = __builtin_amdgcn_mfma_f32_16x16x32_bf16(af[mi], bf[ni], acc[mi][ni], 0, 0, 0);
    }

    #pragma unroll
    for (int mi = 0; mi < 4; ++mi) {
        #pragma unroll
        for (int ni = 0; ni < 4; ++ni) {
            #pragma unroll
            for (int jj = 0; jj < 4; ++jj) {
                const long row = mBase + wr * 64 + mi * 16 + ((lane >> 4) << 2) + jj;
                const long col = nBase + wc * 64 + ni * 16 + (lane & 15);
                const long idx = row * 512 + col;
                float v = acc[mi][ni][jj];
                if (EPI == 1) {
                    float z = v + bias[col];
                    float g = 1.f / (1.f + __expf(-z));
                    Cout[idx] = g * R1[idx] + (1.f - g) * bf2f(R2b[idx]);
                } else {
                    Cout[idx] = v + bias[col] + R1[idx];
                }
            }
        }
    }
}

// ---------- attn3: pure flash MFMA attention on precomputed q/k/v_exp ----------
// (unchanged from round 9 — validated, no longer in the top dispatches)
template<int SEQ, bool TIME>
__launch_bounds__(256)
__global__ void attn3(const ushort_t* __restrict__ qkve, ushort_t* __restrict__ xattn) {
    constexpr int NCH = SEQ / 64;
    constexpr int NQT = SEQ / 64;
    constexpr int NPART = 256 / SEQ;
    constexpr int DCH = 8 / NPART;

    __shared__ short Klds[SEQ][64];
    __shared__ short VTs[64][SEQ];
    __shared__ short Pw[4][16][40];

    const int bx = blockIdx.x;
    const int h = bx & 7;
    const int grp = bx >> 3;
    int tokBase, tokStride;
    if (TIME) {
        const int l = grp & (L_ - 1);
        const int b = grp >> 8;
        tokBase = b * T_ * L_ + l;
        tokStride = L_;
    } else {
        tokBase = grp * L_;
        tokStride = 1;
    }
    const int tid = threadIdx.x;
    const int lane = tid & 63;
    const int w = tid >> 6;

    {
        const int key = tid & (SEQ - 1);
        const int part = tid / SEQ;
        const long tok = tokBase + (long)key * tokStride;
        const ushort_t* kb = qkve + tok * 1536 + 512 + h * 64;
        const ushort_t* vb = qkve + tok * 1536 + 1024 + h * 64;
        #pragma unroll
        for (int c = 0; c < DCH; ++c) {
            const int chunk = part * DCH + c;
            const short8 kv = *(const short8*)(kb + chunk * 8);
            *(short8*)&Klds[key][(chunk ^ (key & 7)) * 8] = kv;
            const short8 vv = *(const short8*)(vb + chunk * 8);
            #pragma unroll
            for (int j = 0; j < 8; ++j) {
                const int d = chunk * 8 + j;
                VTs[d][(((key >> 3) ^ (d & 7)) * 8) + (key & 7)] = vv[j];
            }
        }
    }
    __syncthreads();

    const int l15 = lane & 15;
    const int g = lane >> 4;

    #pragma unroll 1
    for (int qt = 0; qt < NQT; ++qt) {
        const int qbase = qt * 64 + w * 16;
        const long qtok = tokBase + (long)(qbase + l15) * tokStride;

        const ushort_t* qb = qkve + qtok * 1536 + h * 64;
        const short8 Qf0 = *(const short8*)(qb + g * 8);
        const short8 Qf1 = *(const short8*)(qb + 32 + g * 8);

        f32x4 O[4];
        #pragma unroll
        for (int nj = 0; nj < 4; ++nj) { f32x4 z = {0.f,0.f,0.f,0.f}; O[nj] = z; }
        float psum = 0.f;

        #pragma unroll 1
        for (int kb2 = 0; kb2 < NCH; ++kb2) {
            f32x4 S[4];
            #pragma unroll
            for (int f4 = 0; f4 < 4; ++f4) {
                const int row = kb2 * 64 + f4 * 16 + l15;
                const short8 a0 = *(const short8*)&Klds[row][((0 + g) ^ (l15 & 7)) * 8];
                const short8 a1 = *(const short8*)&Klds[row][((4 + g) ^ (l15 & 7)) * 8];
                f32x4 z = {0.f, 0.f, 0.f, 0.f};
                z = __builtin_amdgcn_mfma_f32_16x16x32_bf16(a0, Qf0, z, 0, 0, 0);
                S[f4] = __builtin_amdgcn_mfma_f32_16x16x32_bf16(a1, Qf1, z, 0, 0, 0);
            }
            #pragma unroll
            for (int f4 = 0; f4 < 4; ++f4)
                #pragma unroll
                for (int jj = 0; jj < 4; ++jj) {
                    const float p = __expf(fminf(S[f4][jj], 30.f));
                    S[f4][jj] = p;
                    psum += p;
                }

            #pragma unroll
            for (int sl = 0; sl < 2; ++sl) {
                #pragma unroll
                for (int h2 = 0; h2 < 2; ++h2) {
                    const int f4 = 2 * sl + h2;
                    short4v pv;
                    pv[0] = (short)f2bf(S[f4][0]);
                    pv[1] = (short)f2bf(S[f4][1]);
                    pv[2] = (short)f2bf(S[f4][2]);
                    pv[3] = (short)f2bf(S[f4][3]);
                    *(short4v*)&Pw[w][l15][h2 * 16 + 4 * g] = pv;
                }
                const short8 pa = *(const short8*)&Pw[w][l15][8 * g];
                const int sg = kb2 * 2 + sl;
                #pragma unroll
                for (int nj = 0; nj < 4; ++nj) {
                    const int row = nj * 16 + l15;
                    const short8 bv = *(const short8*)&VTs[row][((4 * sg + g) ^ (l15 & 7)) * 8];
                    O[nj] = __builtin_amdgcn_mfma_f32_16x16x32_bf16(pa, bv, O[nj], 0, 0, 0);
                }
            }
        }

        psum += __shfl_xor(psum, 16);
        psum += __shfl_xor(psum, 32);
        const float inv = 1.f / psum;
        #pragma unroll
        for (int jj = 0; jj < 4; ++jj) {
            const float invq = __shfl(inv, 4 * g + jj);
            const long row = tokBase + (long)(qbase + 4 * g + jj) * tokStride;
            ushort_t* op = xattn + row * 512 + h * 64 + l15;
            #pragma unroll
            for (int nj = 0; nj < 4; ++nj)
                op[nj * 16] = f2bf(O[nj][jj] * invq);
        }
    }
}

// ---------- launch ----------
extern "C" void kernel_launch(void* const* d_in, const int* in_sizes, int n_in,
                              void* d_out, int out_size, void* d_ws, size_t ws_size,
                              hipStream_t stream) {
    const float* x      = (const float*)d_in[0];
    const float* t_Wq   = (const float*)d_in[3];
    const float* t_Wk   = (const float*)d_in[4];
    const float* t_Wv   = (const float*)d_in[5];
    const float* t_U    = (const float*)d_in[6];
    const float* t_V    = (const float*)d_in[7];
    const float* a_Wq   = (const float*)d_in[8];
    const float* a_Wk   = (const float*)d_in[9];
    const float* a_Wv   = (const float*)d_in[10];
    const float* a_U    = (const float*)d_in[11];
    const float* a_V    = (const float*)d_in[12];
    const float* ln1_g  = (const float*)d_in[13];
    const float* ln1_b  = (const float*)d_in[14];
    const float* ln2_g  = (const float*)d_in[15];
    const float* ln2_b  = (const float*)d_in[16];
    const float* ln3_g  = (const float*)d_in[17];
    const float* ln3_b  = (const float*)d_in[18];
    const float* proj_W = (const float*)d_in[19];
    const float* proj_b = (const float*)d_in[20];
    const float* gt_W   = (const float*)d_in[21];
    const float* gt_b   = (const float*)d_in[22];
    const float* ga_W   = (const float*)d_in[23];
    const float* ga_b   = (const float*)d_in[24];
    float* out = (float*)d_out;

    const size_t NC = (size_t)NTOK * 512;
    float* hbuf = (float*)d_ws;                        // phase-A gate out (fp32, 128MB)
    ushort_t* lnb  = (ushort_t*)(hbuf + NC);           // LN out bf16, reused as xatt (64MB)
    ushort_t* qkve = lnb + NC;                         // q/k/v_exp bf16 [NTOK][1536] (192MB)
    float* gout = (float*)qkve;                        // phase-B gate out ALIASES qkve
    ushort_t* Weff = qkve + (size_t)NTOK * 1536;       // folded weights bf16 (1.5MB)
    float* cosT = (float*)(Weff + 1536 * 512);
    float* sinT = cosT + 8192;
    ushort_t* xattb = lnb;

    rope_tables<<<32, 256, 0, stream>>>(cosT, sinT);

    // ===== Phase A: time attention (seq=T, batch=B*L) =====
    fold_w<<<1536, 256, 0, stream>>>(t_Wq, t_Wk, t_Wv, t_U, t_V, Weff);
    lnpack<<<NTOK / 4, 256, 0, stream>>>(x, ln1_g, ln1_b, lnb);
    gemm_qkv3<true><<<3072, 512, 0, stream>>>(lnb, Weff, cosT, sinT, qkve);
    attn3<64, true><<<B_ * L_ * H_, 256, 0, stream>>>(qkve, xattb);
    gemm256<1, true><<<dim3(2, 512), 512, 0, stream>>>(x, nullptr, xattb, gt_W, hbuf, gt_b, x, xattb);

    // ===== Phase B: amino-acid attention (seq=L, batch=B*T) =====
    fold_w<<<1536, 256, 0, stream>>>(a_Wq, a_Wk, a_Wv, a_U, a_V, Weff);
    lnpack<<<NTOK / 4, 256, 0, stream>>>(hbuf, ln2_g, ln2_b, lnb);
    gemm_qkv3<false><<<3072, 512, 0, stream>>>(lnb, Weff, cosT, sinT, qkve);
    attn3<256, false><<<B_ * T_ * H_, 256, 0, stream>>>(qkve, xattb);
    gemm256<1, true><<<dim3(2, 512), 512, 0, stream>>>(hbuf, nullptr, xattb, ga_W, gout, ga_b, hbuf, xattb);

    // ===== Phase C: output projection + residual =====
    lnpack<<<NTOK / 4, 256, 0, stream>>>(gout, ln3_g, ln3_b, lnb);
    gemm256<2, false><<<dim3(2, 512), 512, 0, stream>>>(nullptr, lnb, nullptr, proj_W, out, proj_b, gout, nullptr);
}

// Round 11
// 983.673 us; speedup vs baseline: 1.0998x; 1.0816x over previous
//
#include <hip/hip_runtime.h>

typedef __attribute__((ext_vector_type(8))) short short8;   // 8 bf16
typedef __attribute__((ext_vector_type(4))) short short4v;  // 4 bf16
typedef __attribute__((ext_vector_type(4))) float f32x4;    // MFMA acc
typedef unsigned short ushort_t;
typedef unsigned int uint_t;

#define B_ 4
#define T_ 64
#define L_ 256
#define C_ 512
#define H_ 8
#define NTOK 65536   // B*T*L

// ---------- helpers ----------
__device__ __forceinline__ ushort_t f2bf(float f) {
    uint_t u = __float_as_uint(f);
    u += 0x7FFFu + ((u >> 16) & 1u);   // RNE
    return (ushort_t)(u >> 16);
}
__device__ __forceinline__ float bf2f(ushort_t u) {
    return __uint_as_float((uint_t)u << 16);
}
__device__ __forceinline__ uint_t pk2(float a, float b) {
    return (uint_t)f2bf(a) | ((uint_t)f2bf(b) << 16);
}

// ---------- RoPE tables: cos/sin[pos][i], pos<256, i<32 ----------
__global__ void rope_tables(float* __restrict__ cosT, float* __restrict__ sinT) {
    int idx = blockIdx.x * 256 + threadIdx.x;
    if (idx >= 256 * 32) return;
    int pos = idx >> 5, i = idx & 31;
    float theta = powf(10000.f, -(float)i * (1.f / 32.f));
    float ang = (float)pos * theta;
    float sv, cv;
    sincosf(ang, &sv, &cv);
    cosT[idx] = cv;
    sinT[idx] = sv;
}

// ---------- lnpack: per-token LN(x) -> bf16 row ----------
__global__ void lnpack(const float* __restrict__ xin, const float* __restrict__ lng,
                       const float* __restrict__ lnb, ushort_t* __restrict__ outb) {
    const int lane = threadIdx.x & 63;
    const int w = threadIdx.x >> 6;
    const size_t tok = (size_t)blockIdx.x * 4 + w;
    const float* row = xin + tok * 512 + lane * 8;
    float4 a = *(const float4*)row;
    float4 b = *(const float4*)(row + 4);
    float s = a.x + a.y + a.z + a.w + b.x + b.y + b.z + b.w;
    float q = a.x*a.x + a.y*a.y + a.z*a.z + a.w*a.w + b.x*b.x + b.y*b.y + b.z*b.z + b.w*b.w;
    #pragma unroll
    for (int off = 32; off >= 1; off >>= 1) {
        s += __shfl_xor(s, off);
        q += __shfl_xor(q, off);
    }
    const float m = s * (1.f / 512.f);
    const float v = q * (1.f / 512.f) - m * m;
    const float rs = 1.f / sqrtf(v + 1e-12f);
    float4 gv0 = *(const float4*)(lng + lane * 8);
    float4 gv1 = *(const float4*)(lng + lane * 8 + 4);
    float4 bv0 = *(const float4*)(lnb + lane * 8);
    float4 bv1 = *(const float4*)(lnb + lane * 8 + 4);
    float o0 = (a.x - m) * rs * gv0.x + bv0.x;
    float o1 = (a.y - m) * rs * gv0.y + bv0.y;
    float o2 = (a.z - m) * rs * gv0.z + bv0.z;
    float o3 = (a.w - m) * rs * gv0.w + bv0.w;
    float o4 = (b.x - m) * rs * gv1.x + bv1.x;
    float o5 = (b.y - m) * rs * gv1.y + bv1.y;
    float o6 = (b.z - m) * rs * gv1.z + bv1.z;
    float o7 = (b.w - m) * rs * gv1.w + bv1.w;
    uint4 pk = make_uint4(pk2(o0, o1), pk2(o2, o3), pk2(o4, o5), pk2(o6, o7));
    *(uint4*)(outb + tok * 512 + lane * 8) = pk;
}

// ---------- fold_w: Weff[1536][512] bf16 = [U.Wq*0.125 | U.Wk | V^T.Wv] ----------
__global__ void fold_w(const float* __restrict__ Wq, const float* __restrict__ Wk,
                       const float* __restrict__ Wv, const float* __restrict__ U,
                       const float* __restrict__ V, ushort_t* __restrict__ Weff) {
    const int o = blockIdx.x;               // 0..1535
    const int proj = o >> 9, orow = o & 511;
    const int h = orow >> 6, d = orow & 63;
    const float* W = (proj == 0) ? Wq : (proj == 1) ? Wk : Wv;
    float coef[16];
    #pragma unroll
    for (int r = 0; r < 16; ++r)
        coef[r] = (proj < 2) ? U[h * 1024 + d * 16 + r] : V[h * 1024 + r * 64 + d];
    const float scale = (proj == 0) ? 0.125f : 1.f;   // fold 1/sqrt(64) into q
    for (int c = threadIdx.x; c < 512; c += 256) {
        float acc = 0.f;
        #pragma unroll
        for (int r = 0; r < 16; ++r) acc += coef[r] * W[(h * 16 + r) * 512 + c];
        Weff[(long)o * 512 + c] = f2bf(acc * scale);
    }
}

// ---------- gemm_qkv3: qkve[M][1536] = Ab[M][512] @ Weff^T ----------
// 128x256 tile, 512 threads, A and B both bf16. XCD-swizzled 1D grid (round-10:
// fetch 208->53MB). Epilogue stages bf16 C through an LDS buffer that ALIASES
// the dead As/Bs arena (round-10 lesson: a separate 18KB Ebuf pushed LDS to
// 49KB -> 3 blk/CU -> occupancy 21% -> latency-bound; union keeps 30.7KB ->
// 5 blk/CU). Rope pairs in-lane, 16B coalesced stores.
template<bool TIME>
__launch_bounds__(512)
__global__ void gemm_qkv3(const ushort_t* __restrict__ Ab, const ushort_t* __restrict__ Wb,
                          const float* __restrict__ cosT, const float* __restrict__ sinT,
                          ushort_t* __restrict__ Cout) {
    __shared__ __align__(16) char arena[30720];
    ushort_t (*As)[40]   = (ushort_t (*)[40])arena;            // 128*40*2 = 10240
    ushort_t (*Bs)[40]   = (ushort_t (*)[40])(arena + 10240);  // 256*40*2 = 20480
    ushort_t (*Ebuf)[72] = (ushort_t (*)[72])arena;            // 128*72*2 = 18432 (reuse)

    // XCD-aware swizzle: id%8 = XCD; each XCD owns 64 row panels; a panel's
    // 6 col-blocks run consecutively within one XCD.
    const int id = blockIdx.x;            // 0..3071
    const int xcd = id & 7;
    const int j = id >> 3;                // 0..383
    const int mBase = (xcd * 64 + j / 6) * 128;
    const int nBase = (j % 6) * 256;

    const int tid = threadIdx.x;
    const int ar = tid >> 2;          // 0..127
    const int ak = (tid & 3) << 3;    // 0,8,16,24
    const int br = tid >> 1;          // 0..255
    const int bk = (tid & 1) << 4;    // 0,16
    const long gm = mBase + ar;
    const long gn = nBase + br;

    f32x4 zero = {0.f, 0.f, 0.f, 0.f};
    f32x4 acc[4][4];
    #pragma unroll
    for (int a = 0; a < 4; ++a)
        #pragma unroll
        for (int b = 0; b < 4; ++b) acc[a][b] = zero;

    const int lane = tid & 63;
    const int wid = tid >> 6;
    const int wr = wid >> 2, wc = wid & 3;
    const int arw = wr * 64 + (lane & 15);
    const int brw = wc * 64 + (lane & 15);
    const int ko = (lane >> 4) << 3;
    const int l15 = lane & 15;
    const int g = lane >> 4;

    for (int kt = 0; kt < 512; kt += 32) {
        const short8 av  = *(const short8*)(Ab + gm * 512 + kt + ak);
        const short8 bv0 = *(const short8*)(Wb + gn * 512 + kt + bk);
        const short8 bv1 = *(const short8*)(Wb + gn * 512 + kt + bk + 8);

        __syncthreads();
        *(short8*)&As[ar][ak] = av;
        *(short8*)&Bs[br][bk]     = bv0;
        *(short8*)&Bs[br][bk + 8] = bv1;
        __syncthreads();

        short8 af[4], bf[4];
        #pragma unroll
        for (int mi = 0; mi < 4; ++mi) af[mi] = *(const short8*)&As[arw + mi * 16][ko];
        #pragma unroll
        for (int ni = 0; ni < 4; ++ni) bf[ni] = *(const short8*)&Bs[brw + ni * 16][ko];
        #pragma unroll
        for (int mi = 0; mi < 4; ++mi)
            #pragma unroll
            for (int ni = 0; ni < 4; ++ni)
                acc[mi][ni] = __builtin_amdgcn_mfma_f32_16x16x32_bf16(af[mi], bf[ni], acc[mi][ni], 0, 0, 0);
    }

    // ---- epilogue: 4 stages of 64-col slices through Ebuf (aliases As/Bs) ----
    #pragma unroll 1
    for (int s = 0; s < 4; ++s) {
        __syncthreads();   // prev stage reads done (and k-loop LDS reads on s=0)
        if (wc == s) {
            #pragma unroll
            for (int mi = 0; mi < 4; ++mi)
                #pragma unroll
                for (int ni = 0; ni < 4; ++ni)
                    #pragma unroll
                    for (int jj = 0; jj < 4; ++jj)
                        Ebuf[wr * 64 + mi * 16 + g * 4 + jj][ni * 16 + l15] =
                            f2bf(acc[mi][ni][jj]);
        }
        __syncthreads();
        #pragma unroll
        for (int it = 0; it < 2; ++it) {
            const int u = tid + it * 512;
            const int row = u >> 3, c8 = u & 7;
            short8 v8 = *(const short8*)&Ebuf[row][c8 * 8];
            const long grow = mBase + row;
            const int gcol = nBase + s * 64 + c8 * 8;
            ushort_t* dst = Cout + grow * 1536 + gcol;
            if (gcol < 1024) {   // rope q_exp / k_exp: pairs are in-lane
                const int pos = TIME ? ((int)(grow >> 8) & 63) : ((int)grow & 255);
                const float* cT = cosT + pos * 32 + c8 * 4;
                const float* sT = sinT + pos * 32 + c8 * 4;
                uint_t pkv[4];
                #pragma unroll
                for (int p = 0; p < 4; ++p) {
                    const float cc = cT[p], ss = sT[p];
                    const float re = bf2f((ushort_t)v8[2 * p]);
                    const float im = bf2f((ushort_t)v8[2 * p + 1]);
                    pkv[p] = pk2(re * cc - im * ss, re * ss + im * cc);
                }
                *(uint4*)dst = make_uint4(pkv[0], pkv[1], pkv[2], pkv[3]);
            } else {             // v_exp: straight copy
                *(short8*)dst = v8;
            }
        }
    }
}

// ---------- gemm256: 128x256-tile GEMM (gate / proj paths) ----------
// 1D grid with XCD swizzle: a row-panel's 2 col-blocks run consecutively on
// one XCD so the A panel (fp32, the big fetch) is read from HBM once.
template<int EPI, bool CA>
__launch_bounds__(512)
__global__ void gemm256(const float* __restrict__ A1f, const ushort_t* __restrict__ A1b,
                        const ushort_t* __restrict__ A2b, const float* __restrict__ Bw,
                        float* __restrict__ Cout, const float* __restrict__ bias,
                        const float* __restrict__ R1, const ushort_t* __restrict__ R2b) {
    constexpr int K = CA ? 1024 : 512;
    __shared__ ushort_t As[128][40];
    __shared__ ushort_t Bs[256][40];

    const int id = blockIdx.x;            // 0..1023
    const int xcd = id & 7;
    const int j = id >> 3;                // 0..127
    const int mBase = (xcd * 64 + (j >> 1)) * 128;
    const int nBase = (j & 1) * 256;

    const int tid = threadIdx.x;
    const int ar = tid >> 2;
    const int ak = (tid & 3) << 3;
    const int br = tid >> 1;
    const int bk = (tid & 1) << 4;
    const long gm = mBase + ar;
    const long gn = nBase + br;

    f32x4 zero = {0.f, 0.f, 0.f, 0.f};
    f32x4 acc[4][4];
    #pragma unroll
    for (int a = 0; a < 4; ++a)
        #pragma unroll
        for (int b = 0; b < 4; ++b) acc[a][b] = zero;

    const int lane = tid & 63;
    const int wid = tid >> 6;
    const int wr = wid >> 2, wc = wid & 3;
    const int arw = wr * 64 + (lane & 15);
    const int brw = wc * 64 + (lane & 15);
    const int ko = (lane >> 4) << 3;

    for (int kt = 0; kt < K; kt += 32) {
        const int kb = kt + ak;
        short8 av;
        if (CA) {
            if (kb < 512) {
                const float* ap = A1f + gm * 512 + kb;
                float4 x0 = *(const float4*)(ap);
                float4 x1 = *(const float4*)(ap + 4);
                uint4 p = make_uint4(pk2(x0.x, x0.y), pk2(x0.z, x0.w),
                                     pk2(x1.x, x1.y), pk2(x1.z, x1.w));
                av = *(short8*)&p;
            } else {
                av = *(const short8*)(A2b + gm * 512 + (kb - 512));
            }
        } else {
            av = *(const short8*)(A1b + gm * 512 + kb);
        }
        const float* bp = Bw + gn * (long)K + kt + bk;
        float4 w0 = *(const float4*)(bp);
        float4 w1 = *(const float4*)(bp + 4);
        float4 w2 = *(const float4*)(bp + 8);
        float4 w3 = *(const float4*)(bp + 12);

        __syncthreads();
        *(short8*)&As[ar][ak] = av;
        uint4 pb0 = make_uint4(pk2(w0.x, w0.y), pk2(w0.z, w0.w), pk2(w1.x, w1.y), pk2(w1.z, w1.w));
        uint4 pb1 = make_uint4(pk2(w2.x, w2.y), pk2(w2.z, w2.w), pk2(w3.x, w3.y), pk2(w3.z, w3.w));
        *(uint4*)&Bs[br][bk]     = pb0;
        *(uint4*)&Bs[br][bk + 8] = pb1;
        __syncthreads();

        short8 af[4], bf[4];
        #pragma unroll
        for (int mi = 0; mi < 4; ++mi) af[mi] = *(const short8*)&As[arw + mi * 16][ko];
        #pragma unroll
        for (int ni = 0; ni < 4; ++ni) bf[ni] = *(const short8*)&Bs[brw + ni * 16][ko];
        #pragma unroll
        for (int mi = 0; mi < 4; ++mi)
            #pragma unroll
            for (int ni = 0; ni < 4; ++ni)
                acc[mi][ni] = __builtin_amdgcn_mfma_f32_16x16x32_bf16(af[mi], bf[ni], acc[mi][ni], 0, 0, 0);
    }

    #pragma unroll
    for (int mi = 0; mi < 4; ++mi) {
        #pragma unroll
        for (int ni = 0; ni < 4; ++ni) {
            #pragma unroll
            for (int jj = 0; jj < 4; ++jj) {
                const long row = mBase + wr * 64 + mi * 16 + ((lane >> 4) << 2) + jj;
                const long col = nBase + wc * 64 + ni * 16 + (lane & 15);
                const long idx = row * 512 + col;
                float v = acc[mi][ni][jj];
                if (EPI == 1) {
                    float z = v + bias[col];
                    float g = 1.f / (1.f + __expf(-z));
                    Cout[idx] = g * R1[idx] + (1.f - g) * bf2f(R2b[idx]);
                } else {
                    Cout[idx] = v + bias[col] + R1[idx];
                }
            }
        }
    }
}

// ---------- attn3: pure flash MFMA attention on precomputed q/k/v_exp ----------
template<int SEQ, bool TIME>
__launch_bounds__(256)
__global__ void attn3(const ushort_t* __restrict__ qkve, ushort_t* __restrict__ xattn) {
    constexpr int NCH = SEQ / 64;
    constexpr int NQT = SEQ / 64;
    constexpr int NPART = 256 / SEQ;
    constexpr int DCH = 8 / NPART;

    __shared__ short Klds[SEQ][64];
    __shared__ short VTs[64][SEQ];
    __shared__ short Pw[4][16][40];

    const int bx = blockIdx.x;
    const int h = bx & 7;
    const int grp = bx >> 3;
    int tokBase, tokStride;
    if (TIME) {
        const int l = grp & (L_ - 1);
        const int b = grp >> 8;
        tokBase = b * T_ * L_ + l;
        tokStride = L_;
    } else {
        tokBase = grp * L_;
        tokStride = 1;
    }
    const int tid = threadIdx.x;
    const int lane = tid & 63;
    const int w = tid >> 6;

    {
        const int key = tid & (SEQ - 1);
        const int part = tid / SEQ;
        const long tok = tokBase + (long)key * tokStride;
        const ushort_t* kb = qkve + tok * 1536 + 512 + h * 64;
        const ushort_t* vb = qkve + tok * 1536 + 1024 + h * 64;
        #pragma unroll
        for (int c = 0; c < DCH; ++c) {
            const int chunk = part * DCH + c;
            const short8 kv = *(const short8*)(kb + chunk * 8);
            *(short8*)&Klds[key][(chunk ^ (key & 7)) * 8] = kv;
            const short8 vv = *(const short8*)(vb + chunk * 8);
            #pragma unroll
            for (int j = 0; j < 8; ++j) {
                const int d = chunk * 8 + j;
                VTs[d][(((key >> 3) ^ (d & 7)) * 8) + (key & 7)] = vv[j];
            }
        }
    }
    __syncthreads();

    const int l15 = lane & 15;
    const int g = lane >> 4;

    #pragma unroll 1
    for (int qt = 0; qt < NQT; ++qt) {
        const int qbase = qt * 64 + w * 16;
        const long qtok = tokBase + (long)(qbase + l15) * tokStride;

        const ushort_t* qb = qkve + qtok * 1536 + h * 64;
        const short8 Qf0 = *(const short8*)(qb + g * 8);
        const short8 Qf1 = *(const short8*)(qb + 32 + g * 8);

        f32x4 O[4];
        #pragma unroll
        for (int nj = 0; nj < 4; ++nj) { f32x4 z = {0.f,0.f,0.f,0.f}; O[nj] = z; }
        float psum = 0.f;

        #pragma unroll 1
        for (int kb2 = 0; kb2 < NCH; ++kb2) {
            f32x4 S[4];
            #pragma unroll
            for (int f4 = 0; f4 < 4; ++f4) {
                const int row = kb2 * 64 + f4 * 16 + l15;
                const short8 a0 = *(const short8*)&Klds[row][((0 + g) ^ (l15 & 7)) * 8];
                const short8 a1 = *(const short8*)&Klds[row][((4 + g) ^ (l15 & 7)) * 8];
                f32x4 z = {0.f, 0.f, 0.f, 0.f};
                z = __builtin_amdgcn_mfma_f32_16x16x32_bf16(a0, Qf0, z, 0, 0, 0);
                S[f4] = __builtin_amdgcn_mfma_f32_16x16x32_bf16(a1, Qf1, z, 0, 0, 0);
            }
            #pragma unroll
            for (int f4 = 0; f4 < 4; ++f4)
                #pragma unroll
                for (int jj = 0; jj < 4; ++jj) {
                    const float p = __expf(fminf(S[f4][jj], 30.f));
                    S[f4][jj] = p;
                    psum += p;
                }

            #pragma unroll
            for (int sl = 0; sl < 2; ++sl) {
                #pragma unroll
                for (int h2 = 0; h2 < 2; ++h2) {
                    const int f4 = 2 * sl + h2;
                    short4v pv;
                    pv[0] = (short)f2bf(S[f4][0]);
                    pv[1] = (short)f2bf(S[f4][1]);
                    pv[2] = (short)f2bf(S[f4][2]);
                    pv[3] = (short)f2bf(S[f4][3]);
                    *(short4v*)&Pw[w][l15][h2 * 16 + 4 * g] = pv;
                }
                const short8 pa = *(const short8*)&Pw[w][l15][8 * g];
                const int sg = kb2 * 2 + sl;
                #pragma unroll
                for (int nj = 0; nj < 4; ++nj) {
                    const int row = nj * 16 + l15;
                    const short8 bv = *(const short8*)&VTs[row][((4 * sg + g) ^ (l15 & 7)) * 8];
                    O[nj] = __builtin_amdgcn_mfma_f32_16x16x32_bf16(pa, bv, O[nj], 0, 0, 0);
                }
            }
        }

        psum += __shfl_xor(psum, 16);
        psum += __shfl_xor(psum, 32);
        const float inv = 1.f / psum;
        #pragma unroll
        for (int jj = 0; jj < 4; ++jj) {
            const float invq = __shfl(inv, 4 * g + jj);
            const long row = tokBase + (long)(qbase + 4 * g + jj) * tokStride;
            ushort_t* op = xattn + row * 512 + h * 64 + l15;
            #pragma unroll
            for (int nj = 0; nj < 4; ++nj)
                op[nj * 16] = f2bf(O[nj][jj] * invq);
        }
    }
}

// ---------- launch ----------
extern "C" void kernel_launch(void* const* d_in, const int* in_sizes, int n_in,
                              void* d_out, int out_size, void* d_ws, size_t ws_size,
                              hipStream_t stream) {
    const float* x      = (const float*)d_in[0];
    const float* t_Wq   = (const float*)d_in[3];
    const float* t_Wk   = (const float*)d_in[4];
    const float* t_Wv   = (const float*)d_in[5];
    const float* t_U    = (const float*)d_in[6];
    const float* t_V    = (const float*)d_in[7];
    const float* a_Wq   = (const float*)d_in[8];
    const float* a_Wk   = (const float*)d_in[9];
    const float* a_Wv   = (const float*)d_in[10];
    const float* a_U    = (const float*)d_in[11];
    const float* a_V    = (const float*)d_in[12];
    const float* ln1_g  = (const float*)d_in[13];
    const float* ln1_b  = (const float*)d_in[14];
    const float* ln2_g  = (const float*)d_in[15];
    const float* ln2_b  = (const float*)d_in[16];
    const float* ln3_g  = (const float*)d_in[17];
    const float* ln3_b  = (const float*)d_in[18];
    const float* proj_W = (const float*)d_in[19];
    const float* proj_b = (const float*)d_in[20];
    const float* gt_W   = (const float*)d_in[21];
    const float* gt_b   = (const float*)d_in[22];
    const float* ga_W   = (const float*)d_in[23];
    const float* ga_b   = (const float*)d_in[24];
    float* out = (float*)d_out;

    const size_t NC = (size_t)NTOK * 512;
    float* hbuf = (float*)d_ws;                        // phase-A gate out (fp32, 128MB)
    ushort_t* lnb  = (ushort_t*)(hbuf + NC);           // LN out bf16, reused as xatt (64MB)
    ushort_t* qkve = lnb + NC;                         // q/k/v_exp bf16 [NTOK][1536] (192MB)
    float* gout = (float*)qkve;                        // phase-B gate out ALIASES qkve
    ushort_t* Weff = qkve + (size_t)NTOK * 1536;       // folded weights bf16 (1.5MB)
    float* cosT = (float*)(Weff + 1536 * 512);
    float* sinT = cosT + 8192;
    ushort_t* xattb = lnb;

    rope_tables<<<32, 256, 0, stream>>>(cosT, sinT);

    // ===== Phase A: time attention (seq=T, batch=B*L) =====
    fold_w<<<1536, 256, 0, stream>>>(t_Wq, t_Wk, t_Wv, t_U, t_V, Weff);
    lnpack<<<NTOK / 4, 256, 0, stream>>>(x, ln1_g, ln1_b, lnb);
    gemm_qkv3<true><<<3072, 512, 0, stream>>>(lnb, Weff, cosT, sinT, qkve);
    attn3<64, true><<<B_ * L_ * H_, 256, 0, stream>>>(qkve, xattb);
    gemm256<1, true><<<1024, 512, 0, stream>>>(x, nullptr, xattb, gt_W, hbuf, gt_b, x, xattb);

    // ===== Phase B: amino-acid attention (seq=L, batch=B*T) =====
    fold_w<<<1536, 256, 0, stream>>>(a_Wq, a_Wk, a_Wv, a_U, a_V, Weff);
    lnpack<<<NTOK / 4, 256, 0, stream>>>(hbuf, ln2_g, ln2_b, lnb);
    gemm_qkv3<false><<<3072, 512, 0, stream>>>(lnb, Weff, cosT, sinT, qkve);
    attn3<256, false><<<B_ * T_ * H_, 256, 0, stream>>>(qkve, xattb);
    gemm256<1, true><<<1024, 512, 0, stream>>>(hbuf, nullptr, xattb, ga_W, gout, ga_b, hbuf, xattb);

    // ===== Phase C: output projection + residual =====
    lnpack<<<NTOK / 4, 256, 0, stream>>>(gout, ln3_g, ln3_b, lnb);
    gemm256<2, false><<<1024, 512, 0, stream>>>(nullptr, lnb, nullptr, proj_W, out, proj_b, gout, nullptr);
}

// Round 12
// 863.978 us; speedup vs baseline: 1.2521x; 1.1385x over previous
//
#include <hip/hip_runtime.h>

typedef __attribute__((ext_vector_type(8))) short short8;   // 8 bf16
typedef __attribute__((ext_vector_type(4))) short short4v;  // 4 bf16
typedef __attribute__((ext_vector_type(4))) float f32x4;    // MFMA acc
typedef unsigned short ushort_t;
typedef unsigned int uint_t;

#define B_ 4
#define T_ 64
#define L_ 256
#define C_ 512
#define H_ 8
#define NTOK 65536   // B*T*L

// ---------- helpers ----------
__device__ __forceinline__ ushort_t f2bf(float f) {
    uint_t u = __float_as_uint(f);
    u += 0x7FFFu + ((u >> 16) & 1u);   // RNE
    return (ushort_t)(u >> 16);
}
__device__ __forceinline__ float bf2f(ushort_t u) {
    return __uint_as_float((uint_t)u << 16);
}
__device__ __forceinline__ uint_t pk2(float a, float b) {
    return (uint_t)f2bf(a) | ((uint_t)f2bf(b) << 16);
}

// ---------- RoPE tables: cos/sin[pos][i], pos<256, i<32 ----------
__global__ void rope_tables(float* __restrict__ cosT, float* __restrict__ sinT) {
    int idx = blockIdx.x * 256 + threadIdx.x;
    if (idx >= 256 * 32) return;
    int pos = idx >> 5, i = idx & 31;
    float theta = powf(10000.f, -(float)i * (1.f / 32.f));
    float ang = (float)pos * theta;
    float sv, cv;
    sincosf(ang, &sv, &cv);
    cosT[idx] = cv;
    sinT[idx] = sv;
}

// ---------- packw: fp32 -> bf16 weight pack ----------
__global__ void packw(const float* __restrict__ src, ushort_t* __restrict__ dst, int n) {
    const int i = (blockIdx.x * 256 + threadIdx.x) * 4;
    if (i < n) {
        float4 v = *(const float4*)(src + i);
        *(uint2*)(dst + i) = make_uint2(pk2(v.x, v.y), pk2(v.z, v.w));
    }
}

// ---------- lnpack_f: fp32 input -> LN bf16 out (+ optional raw bf16 pack) ----------
template<bool RAW>
__global__ void lnpack_f(const float* __restrict__ xin, const float* __restrict__ lng,
                         const float* __restrict__ lnbias, ushort_t* __restrict__ outb,
                         ushort_t* __restrict__ rawb) {
    const int lane = threadIdx.x & 63;
    const int w = threadIdx.x >> 6;
    const size_t tok = (size_t)blockIdx.x * 4 + w;
    const float* row = xin + tok * 512 + lane * 8;
    float4 a = *(const float4*)row;
    float4 b = *(const float4*)(row + 4);
    if (RAW) {
        uint4 rp = make_uint4(pk2(a.x, a.y), pk2(a.z, a.w), pk2(b.x, b.y), pk2(b.z, b.w));
        *(uint4*)(rawb + tok * 512 + lane * 8) = rp;
    }
    float s = a.x + a.y + a.z + a.w + b.x + b.y + b.z + b.w;
    float q = a.x*a.x + a.y*a.y + a.z*a.z + a.w*a.w + b.x*b.x + b.y*b.y + b.z*b.z + b.w*b.w;
    #pragma unroll
    for (int off = 32; off >= 1; off >>= 1) {
        s += __shfl_xor(s, off);
        q += __shfl_xor(q, off);
    }
    const float m = s * (1.f / 512.f);
    const float v = q * (1.f / 512.f) - m * m;
    const float rs = 1.f / sqrtf(v + 1e-12f);
    float4 gv0 = *(const float4*)(lng + lane * 8);
    float4 gv1 = *(const float4*)(lng + lane * 8 + 4);
    float4 bv0 = *(const float4*)(lnbias + lane * 8);
    float4 bv1 = *(const float4*)(lnbias + lane * 8 + 4);
    float o0 = (a.x - m) * rs * gv0.x + bv0.x;
    float o1 = (a.y - m) * rs * gv0.y + bv0.y;
    float o2 = (a.z - m) * rs * gv0.z + bv0.z;
    float o3 = (a.w - m) * rs * gv0.w + bv0.w;
    float o4 = (b.x - m) * rs * gv1.x + bv1.x;
    float o5 = (b.y - m) * rs * gv1.y + bv1.y;
    float o6 = (b.z - m) * rs * gv1.z + bv1.z;
    float o7 = (b.w - m) * rs * gv1.w + bv1.w;
    uint4 pk = make_uint4(pk2(o0, o1), pk2(o2, o3), pk2(o4, o5), pk2(o6, o7));
    *(uint4*)(outb + tok * 512 + lane * 8) = pk;
}

// ---------- lnpack_h: bf16 input -> LN bf16 out ----------
__global__ void lnpack_h(const ushort_t* __restrict__ xin, const float* __restrict__ lng,
                         const float* __restrict__ lnbias, ushort_t* __restrict__ outb) {
    const int lane = threadIdx.x & 63;
    const int w = threadIdx.x >> 6;
    const size_t tok = (size_t)blockIdx.x * 4 + w;
    const short8* rp = (const short8*)(xin + tok * 512 + lane * 8);
    const short8 r = rp[0];
    float x[8];
    #pragma unroll
    for (int jv = 0; jv < 8; ++jv) x[jv] = bf2f((ushort_t)r[jv]);
    float s = 0.f, q = 0.f;
    #pragma unroll
    for (int jv = 0; jv < 8; ++jv) { s += x[jv]; q += x[jv] * x[jv]; }
    #pragma unroll
    for (int off = 32; off >= 1; off >>= 1) {
        s += __shfl_xor(s, off);
        q += __shfl_xor(q, off);
    }
    const float m = s * (1.f / 512.f);
    const float v = q * (1.f / 512.f) - m * m;
    const float rs = 1.f / sqrtf(v + 1e-12f);
    float4 gv0 = *(const float4*)(lng + lane * 8);
    float4 gv1 = *(const float4*)(lng + lane * 8 + 4);
    float4 bv0 = *(const float4*)(lnbias + lane * 8);
    float4 bv1 = *(const float4*)(lnbias + lane * 8 + 4);
    float o[8];
    o[0] = (x[0] - m) * rs * gv0.x + bv0.x;
    o[1] = (x[1] - m) * rs * gv0.y + bv0.y;
    o[2] = (x[2] - m) * rs * gv0.z + bv0.z;
    o[3] = (x[3] - m) * rs * gv0.w + bv0.w;
    o[4] = (x[4] - m) * rs * gv1.x + bv1.x;
    o[5] = (x[5] - m) * rs * gv1.y + bv1.y;
    o[6] = (x[6] - m) * rs * gv1.z + bv1.z;
    o[7] = (x[7] - m) * rs * gv1.w + bv1.w;
    uint4 pk = make_uint4(pk2(o[0], o[1]), pk2(o[2], o[3]), pk2(o[4], o[5]), pk2(o[6], o[7]));
    *(uint4*)(outb + tok * 512 + lane * 8) = pk;
}

// ---------- fold_w: Weff[1536][512] bf16 = [U.Wq*0.125 | U.Wk | V^T.Wv] ----------
__global__ void fold_w(const float* __restrict__ Wq, const float* __restrict__ Wk,
                       const float* __restrict__ Wv, const float* __restrict__ U,
                       const float* __restrict__ V, ushort_t* __restrict__ Weff) {
    const int o = blockIdx.x;               // 0..1535
    const int proj = o >> 9, orow = o & 511;
    const int h = orow >> 6, d = orow & 63;
    const float* W = (proj == 0) ? Wq : (proj == 1) ? Wk : Wv;
    float coef[16];
    #pragma unroll
    for (int r = 0; r < 16; ++r)
        coef[r] = (proj < 2) ? U[h * 1024 + d * 16 + r] : V[h * 1024 + r * 64 + d];
    const float scale = (proj == 0) ? 0.125f : 1.f;   // fold 1/sqrt(64) into q
    for (int c = threadIdx.x; c < 512; c += 256) {
        float acc = 0.f;
        #pragma unroll
        for (int r = 0; r < 16; ++r) acc += coef[r] * W[(h * 16 + r) * 512 + c];
        Weff[(long)o * 512 + c] = f2bf(acc * scale);
    }
}

// ---------- gemm_qkv3: qkve[M][1536] = Ab[M][512] @ Weff^T (unchanged r11) ----------
template<bool TIME>
__launch_bounds__(512)
__global__ void gemm_qkv3(const ushort_t* __restrict__ Ab, const ushort_t* __restrict__ Wb,
                          const float* __restrict__ cosT, const float* __restrict__ sinT,
                          ushort_t* __restrict__ Cout) {
    __shared__ __align__(16) char arena[30720];
    ushort_t (*As)[40]   = (ushort_t (*)[40])arena;            // 10240 B
    ushort_t (*Bs)[40]   = (ushort_t (*)[40])(arena + 10240);  // 20480 B
    ushort_t (*Ebuf)[72] = (ushort_t (*)[72])arena;            // 18432 B (reuse)

    const int id = blockIdx.x;            // 0..3071
    const int xcd = id & 7;
    const int j = id >> 3;                // 0..383
    const int mBase = (xcd * 64 + j / 6) * 128;
    const int nBase = (j % 6) * 256;

    const int tid = threadIdx.x;
    const int ar = tid >> 2;
    const int ak = (tid & 3) << 3;
    const int br = tid >> 1;
    const int bk = (tid & 1) << 4;
    const long gm = mBase + ar;
    const long gn = nBase + br;

    f32x4 zero = {0.f, 0.f, 0.f, 0.f};
    f32x4 acc[4][4];
    #pragma unroll
    for (int a = 0; a < 4; ++a)
        #pragma unroll
        for (int b = 0; b < 4; ++b) acc[a][b] = zero;

    const int lane = tid & 63;
    const int wid = tid >> 6;
    const int wr = wid >> 2, wc = wid & 3;
    const int arw = wr * 64 + (lane & 15);
    const int brw = wc * 64 + (lane & 15);
    const int ko = (lane >> 4) << 3;
    const int l15 = lane & 15;
    const int g = lane >> 4;

    for (int kt = 0; kt < 512; kt += 32) {
        const short8 av  = *(const short8*)(Ab + gm * 512 + kt + ak);
        const short8 bv0 = *(const short8*)(Wb + gn * 512 + kt + bk);
        const short8 bv1 = *(const short8*)(Wb + gn * 512 + kt + bk + 8);

        __syncthreads();
        *(short8*)&As[ar][ak] = av;
        *(short8*)&Bs[br][bk]     = bv0;
        *(short8*)&Bs[br][bk + 8] = bv1;
        __syncthreads();

        short8 af[4], bf[4];
        #pragma unroll
        for (int mi = 0; mi < 4; ++mi) af[mi] = *(const short8*)&As[arw + mi * 16][ko];
        #pragma unroll
        for (int ni = 0; ni < 4; ++ni) bf[ni] = *(const short8*)&Bs[brw + ni * 16][ko];
        #pragma unroll
        for (int mi = 0; mi < 4; ++mi)
            #pragma unroll
            for (int ni = 0; ni < 4; ++ni)
                acc[mi][ni] = __builtin_amdgcn_mfma_f32_16x16x32_bf16(af[mi], bf[ni], acc[mi][ni], 0, 0, 0);
    }

    // ---- epilogue: 4 stages of 64-col slices through Ebuf (aliases As/Bs) ----
    #pragma unroll 1
    for (int s = 0; s < 4; ++s) {
        __syncthreads();
        if (wc == s) {
            #pragma unroll
            for (int mi = 0; mi < 4; ++mi)
                #pragma unroll
                for (int ni = 0; ni < 4; ++ni)
                    #pragma unroll
                    for (int jj = 0; jj < 4; ++jj)
                        Ebuf[wr * 64 + mi * 16 + g * 4 + jj][ni * 16 + l15] =
                            f2bf(acc[mi][ni][jj]);
        }
        __syncthreads();
        #pragma unroll
        for (int it = 0; it < 2; ++it) {
            const int u = tid + it * 512;
            const int row = u >> 3, c8 = u & 7;
            short8 v8 = *(const short8*)&Ebuf[row][c8 * 8];
            const long grow = mBase + row;
            const int gcol = nBase + s * 64 + c8 * 8;
            ushort_t* dst = Cout + grow * 1536 + gcol;
            if (gcol < 1024) {   // rope q_exp / k_exp: pairs are in-lane
                const int pos = TIME ? ((int)(grow >> 8) & 63) : ((int)grow & 255);
                const float* cT = cosT + pos * 32 + c8 * 4;
                const float* sT = sinT + pos * 32 + c8 * 4;
                uint_t pkv[4];
                #pragma unroll
                for (int p = 0; p < 4; ++p) {
                    const float cc = cT[p], ss = sT[p];
                    const float re = bf2f((ushort_t)v8[2 * p]);
                    const float im = bf2f((ushort_t)v8[2 * p + 1]);
                    pkv[p] = pk2(re * cc - im * ss, re * ss + im * cc);
                }
                *(uint4*)dst = make_uint4(pkv[0], pkv[1], pkv[2], pkv[3]);
            } else {             // v_exp: straight copy
                *(short8*)dst = v8;
            }
        }
    }
}

// ---------- gemm256: all-bf16 128x256-tile GEMM (gate / proj paths) ----------
// EPI 1 (gate, K=1024): g = sigmoid(acc+bias); out_bf16 = g*R1b + (1-g)*R2b
// EPI 2 (proj, K=512):  out_f32 = acc + bias + R1b
// XCD-swizzled 1D grid (panel's 2 col-blocks on one XCD). All operands bf16 ->
// k-loop has zero pack VALU (round-11 lesson: fp32 staging = 32% VALUBusy and
// double-width fetch of the residual stream).
template<int EPI>
__launch_bounds__(512)
__global__ void gemm256(const ushort_t* __restrict__ A1b, const ushort_t* __restrict__ A2b,
                        const ushort_t* __restrict__ Bwb, void* __restrict__ Cout_,
                        const float* __restrict__ bias, const ushort_t* __restrict__ R1b,
                        const ushort_t* __restrict__ R2b) {
    constexpr int K = (EPI == 1) ? 1024 : 512;
    __shared__ ushort_t As[128][40];
    __shared__ ushort_t Bs[256][40];

    const int id = blockIdx.x;            // 0..1023
    const int xcd = id & 7;
    const int j = id >> 3;                // 0..127
    const int mBase = (xcd * 64 + (j >> 1)) * 128;
    const int nBase = (j & 1) * 256;

    const int tid = threadIdx.x;
    const int ar = tid >> 2;
    const int ak = (tid & 3) << 3;
    const int br = tid >> 1;
    const int bk = (tid & 1) << 4;
    const long gm = mBase + ar;
    const long gn = nBase + br;

    f32x4 zero = {0.f, 0.f, 0.f, 0.f};
    f32x4 acc[4][4];
    #pragma unroll
    for (int a = 0; a < 4; ++a)
        #pragma unroll
        for (int b = 0; b < 4; ++b) acc[a][b] = zero;

    const int lane = tid & 63;
    const int wid = tid >> 6;
    const int wr = wid >> 2, wc = wid & 3;
    const int arw = wr * 64 + (lane & 15);
    const int brw = wc * 64 + (lane & 15);
    const int ko = (lane >> 4) << 3;

    for (int kt = 0; kt < K; kt += 32) {
        const int kb = kt + ak;
        short8 av;
        if (EPI == 1) {
            av = (kb < 512) ? *(const short8*)(A1b + gm * 512 + kb)
                            : *(const short8*)(A2b + gm * 512 + (kb - 512));
        } else {
            av = *(const short8*)(A1b + gm * 512 + kb);
        }
        const short8 bv0 = *(const short8*)(Bwb + gn * (long)K + kt + bk);
        const short8 bv1 = *(const short8*)(Bwb + gn * (long)K + kt + bk + 8);

        __syncthreads();
        *(short8*)&As[ar][ak] = av;
        *(short8*)&Bs[br][bk]     = bv0;
        *(short8*)&Bs[br][bk + 8] = bv1;
        __syncthreads();

        short8 af[4], bf[4];
        #pragma unroll
        for (int mi = 0; mi < 4; ++mi) af[mi] = *(const short8*)&As[arw + mi * 16][ko];
        #pragma unroll
        for (int ni = 0; ni < 4; ++ni) bf[ni] = *(const short8*)&Bs[brw + ni * 16][ko];
        #pragma unroll
        for (int mi = 0; mi < 4; ++mi)
            #pragma unroll
            for (int ni = 0; ni < 4; ++ni)
                acc[mi][ni] = __builtin_amdgcn_mfma_f32_16x16x32_bf16(af[mi], bf[ni], acc[mi][ni], 0, 0, 0);
    }

    #pragma unroll
    for (int mi = 0; mi < 4; ++mi) {
        #pragma unroll
        for (int ni = 0; ni < 4; ++ni) {
            #pragma unroll
            for (int jj = 0; jj < 4; ++jj) {
                const long row = mBase + wr * 64 + mi * 16 + ((lane >> 4) << 2) + jj;
                const long col = nBase + wc * 64 + ni * 16 + (lane & 15);
                const long idx = row * 512 + col;
                const float v = acc[mi][ni][jj];
                if (EPI == 1) {
                    const float z = v + bias[col];
                    const float gg = 1.f / (1.f + __expf(-z));
                    const float o = gg * bf2f(R1b[idx]) + (1.f - gg) * bf2f(R2b[idx]);
                    ((ushort_t*)Cout_)[idx] = f2bf(o);
                } else {
                    ((float*)Cout_)[idx] = v + bias[col] + bf2f(R1b[idx]);
                }
            }
        }
    }
}

// ---------- attn3: pure flash MFMA attention on precomputed q/k/v_exp ----------
template<int SEQ, bool TIME>
__launch_bounds__(256)
__global__ void attn3(const ushort_t* __restrict__ qkve, ushort_t* __restrict__ xattn) {
    constexpr int NCH = SEQ / 64;
    constexpr int NQT = SEQ / 64;
    constexpr int NPART = 256 / SEQ;
    constexpr int DCH = 8 / NPART;

    __shared__ short Klds[SEQ][64];
    __shared__ short VTs[64][SEQ];
    __shared__ short Pw[4][16][40];

    const int bx = blockIdx.x;
    const int h = bx & 7;
    const int grp = bx >> 3;
    int tokBase, tokStride;
    if (TIME) {
        const int l = grp & (L_ - 1);
        const int b = grp >> 8;
        tokBase = b * T_ * L_ + l;
        tokStride = L_;
    } else {
        tokBase = grp * L_;
        tokStride = 1;
    }
    const int tid = threadIdx.x;
    const int lane = tid & 63;
    const int w = tid >> 6;

    {
        const int key = tid & (SEQ - 1);
        const int part = tid / SEQ;
        const long tok = tokBase + (long)key * tokStride;
        const ushort_t* kb = qkve + tok * 1536 + 512 + h * 64;
        const ushort_t* vb = qkve + tok * 1536 + 1024 + h * 64;
        #pragma unroll
        for (int c = 0; c < DCH; ++c) {
            const int chunk = part * DCH + c;
            const short8 kv = *(const short8*)(kb + chunk * 8);
            *(short8*)&Klds[key][(chunk ^ (key & 7)) * 8] = kv;
            const short8 vv = *(const short8*)(vb + chunk * 8);
            #pragma unroll
            for (int jx = 0; jx < 8; ++jx) {
                const int d = chunk * 8 + jx;
                VTs[d][(((key >> 3) ^ (d & 7)) * 8) + (key & 7)] = vv[jx];
            }
        }
    }
    __syncthreads();

    const int l15 = lane & 15;
    const int g = lane >> 4;

    #pragma unroll 1
    for (int qt = 0; qt < NQT; ++qt) {
        const int qbase = qt * 64 + w * 16;
        const long qtok = tokBase + (long)(qbase + l15) * tokStride;

        const ushort_t* qb = qkve + qtok * 1536 + h * 64;
        const short8 Qf0 = *(const short8*)(qb + g * 8);
        const short8 Qf1 = *(const short8*)(qb + 32 + g * 8);

        f32x4 O[4];
        #pragma unroll
        for (int nj = 0; nj < 4; ++nj) { f32x4 z = {0.f,0.f,0.f,0.f}; O[nj] = z; }
        float psum = 0.f;

        #pragma unroll 1
        for (int kb2 = 0; kb2 < NCH; ++kb2) {
            f32x4 S[4];
            #pragma unroll
            for (int f4 = 0; f4 < 4; ++f4) {
                const int row = kb2 * 64 + f4 * 16 + l15;
                const short8 a0 = *(const short8*)&Klds[row][((0 + g) ^ (l15 & 7)) * 8];
                const short8 a1 = *(const short8*)&Klds[row][((4 + g) ^ (l15 & 7)) * 8];
                f32x4 z = {0.f, 0.f, 0.f, 0.f};
                z = __builtin_amdgcn_mfma_f32_16x16x32_bf16(a0, Qf0, z, 0, 0, 0);
                S[f4] = __builtin_amdgcn_mfma_f32_16x16x32_bf16(a1, Qf1, z, 0, 0, 0);
            }
            #pragma unroll
            for (int f4 = 0; f4 < 4; ++f4)
                #pragma unroll
                for (int jj = 0; jj < 4; ++jj) {
                    const float p = __expf(fminf(S[f4][jj], 30.f));
                    S[f4][jj] = p;
                    psum += p;
                }

            #pragma unroll
            for (int sl = 0; sl < 2; ++sl) {
                #pragma unroll
                for (int h2 = 0; h2 < 2; ++h2) {
                    const int f4 = 2 * sl + h2;
                    short4v pv;
                    pv[0] = (short)f2bf(S[f4][0]);
                    pv[1] = (short)f2bf(S[f4][1]);
                    pv[2] = (short)f2bf(S[f4][2]);
                    pv[3] = (short)f2bf(S[f4][3]);
                    *(short4v*)&Pw[w][l15][h2 * 16 + 4 * g] = pv;
                }
                const short8 pa = *(const short8*)&Pw[w][l15][8 * g];
                const int sg = kb2 * 2 + sl;
                #pragma unroll
                for (int nj = 0; nj < 4; ++nj) {
                    const int row = nj * 16 + l15;
                    const short8 bv = *(const short8*)&VTs[row][((4 * sg + g) ^ (l15 & 7)) * 8];
                    O[nj] = __builtin_amdgcn_mfma_f32_16x16x32_bf16(pa, bv, O[nj], 0, 0, 0);
                }
            }
        }

        psum += __shfl_xor(psum, 16);
        psum += __shfl_xor(psum, 32);
        const float inv = 1.f / psum;
        #pragma unroll
        for (int jj = 0; jj < 4; ++jj) {
            const float invq = __shfl(inv, 4 * g + jj);
            const long row = tokBase + (long)(qbase + 4 * g + jj) * tokStride;
            ushort_t* op = xattn + row * 512 + h * 64 + l15;
            #pragma unroll
            for (int nj = 0; nj < 4; ++nj)
                op[nj * 16] = f2bf(O[nj][jj] * invq);
        }
    }
}

// ---------- launch ----------
extern "C" void kernel_launch(void* const* d_in, const int* in_sizes, int n_in,
                              void* d_out, int out_size, void* d_ws, size_t ws_size,
                              hipStream_t stream) {
    const float* x      = (const float*)d_in[0];
    const float* t_Wq   = (const float*)d_in[3];
    const float* t_Wk   = (const float*)d_in[4];
    const float* t_Wv   = (const float*)d_in[5];
    const float* t_U    = (const float*)d_in[6];
    const float* t_V    = (const float*)d_in[7];
    const float* a_Wq   = (const float*)d_in[8];
    const float* a_Wk   = (const float*)d_in[9];
    const float* a_Wv   = (const float*)d_in[10];
    const float* a_U    = (const float*)d_in[11];
    const float* a_V    = (const float*)d_in[12];
    const float* ln1_g  = (const float*)d_in[13];
    const float* ln1_b  = (const float*)d_in[14];
    const float* ln2_g  = (const float*)d_in[15];
    const float* ln2_b  = (const float*)d_in[16];
    const float* ln3_g  = (const float*)d_in[17];
    const float* ln3_b  = (const float*)d_in[18];
    const float* proj_W = (const float*)d_in[19];
    const float* proj_b = (const float*)d_in[20];
    const float* gt_W   = (const float*)d_in[21];
    const float* gt_b   = (const float*)d_in[22];
    const float* ga_W   = (const float*)d_in[23];
    const float* ga_b   = (const float*)d_in[24];
    float* out = (float*)d_out;

    const size_t NC = (size_t)NTOK * 512;
    ushort_t* xb   = (ushort_t*)d_ws;                  // bf16(x), 64MB — dead after gate A
    ushort_t* lnb  = xb + NC;                          // LN out / xatt bf16, 64MB
    ushort_t* resA = lnb + NC;                         // phase-A residual bf16, 64MB
    ushort_t* qkve = resA + NC;                        // q/k/v_exp bf16 [NTOK][1536], 192MB
    ushort_t* resB = qkve;                             // phase-B residual ALIASES qkve
                                                       // (qkve dead after attn3 B)
    ushort_t* Weff = qkve + (size_t)NTOK * 1536;       // folded attn weights, 1.5MB
    ushort_t* gtWb = Weff + 1536 * 512;                // gate-A weights bf16, 1MB
    ushort_t* gaWb = gtWb + 512 * 1024;                // gate-B weights bf16, 1MB
    ushort_t* prWb = gaWb + 512 * 1024;                // proj weights bf16, 0.5MB
    float* cosT = (float*)(prWb + 512 * 512);
    float* sinT = cosT + 8192;
    ushort_t* xattb = lnb;

    rope_tables<<<32, 256, 0, stream>>>(cosT, sinT);
    packw<<<512, 256, 0, stream>>>(gt_W, gtWb, 512 * 1024);
    packw<<<512, 256, 0, stream>>>(ga_W, gaWb, 512 * 1024);
    packw<<<256, 256, 0, stream>>>(proj_W, prWb, 512 * 512);

    // ===== Phase A: time attention (seq=T, batch=B*L) =====
    fold_w<<<1536, 256, 0, stream>>>(t_Wq, t_Wk, t_Wv, t_U, t_V, Weff);
    lnpack_f<true><<<NTOK / 4, 256, 0, stream>>>(x, ln1_g, ln1_b, lnb, xb);
    gemm_qkv3<true><<<3072, 512, 0, stream>>>(lnb, Weff, cosT, sinT, qkve);
    attn3<64, true><<<B_ * L_ * H_, 256, 0, stream>>>(qkve, xattb);
    gemm256<1><<<1024, 512, 0, stream>>>(xb, xattb, gtWb, resA, gt_b, xb, xattb);

    // ===== Phase B: amino-acid attention (seq=L, batch=B*T) =====
    fold_w<<<1536, 256, 0, stream>>>(a_Wq, a_Wk, a_Wv, a_U, a_V, Weff);
    lnpack_h<<<NTOK / 4, 256, 0, stream>>>(resA, ln2_g, ln2_b, lnb);
    gemm_qkv3<false><<<3072, 512, 0, stream>>>(lnb, Weff, cosT, sinT, qkve);
    attn3<256, false><<<B_ * T_ * H_, 256, 0, stream>>>(qkve, xattb);
    gemm256<1><<<1024, 512, 0, stream>>>(resA, xattb, gaWb, resB, ga_b, resA, xattb);

    // ===== Phase C: output projection + residual =====
    lnpack_h<<<NTOK / 4, 256, 0, stream>>>(resB, ln3_g, ln3_b, lnb);
    gemm256<2><<<1024, 512, 0, stream>>>(lnb, nullptr, prWb, out, proj_b, resB, nullptr);
}

// Round 13
// 813.250 us; speedup vs baseline: 1.3302x; 1.0624x over previous
//
#include <hip/hip_runtime.h>

typedef __attribute__((ext_vector_type(8))) short short8;   // 8 bf16
typedef __attribute__((ext_vector_type(4))) short short4v;  // 4 bf16
typedef __attribute__((ext_vector_type(4))) float f32x4;    // MFMA acc
typedef unsigned short ushort_t;
typedef unsigned int uint_t;

#define B_ 4
#define T_ 64
#define L_ 256
#define C_ 512
#define H_ 8
#define NTOK 65536   // B*T*L

// ---------- helpers ----------
__device__ __forceinline__ ushort_t f2bf(float f) {
    uint_t u = __float_as_uint(f);
    u += 0x7FFFu + ((u >> 16) & 1u);   // RNE
    return (ushort_t)(u >> 16);
}
__device__ __forceinline__ float bf2f(ushort_t u) {
    return __uint_as_float((uint_t)u << 16);
}
__device__ __forceinline__ uint_t pk2(float a, float b) {
    return (uint_t)f2bf(a) | ((uint_t)f2bf(b) << 16);
}
// async global->LDS, 16B per lane; lds base must be wave-uniform (HW adds lane*16)
__device__ __forceinline__ void gload16(const ushort_t* __restrict__ g, ushort_t* l) {
    __builtin_amdgcn_global_load_lds(
        (const __attribute__((address_space(1))) void*)g,
        (__attribute__((address_space(3))) void*)l,
        16, 0, 0);
}

// ---------- RoPE tables: cos/sin[pos][i], pos<256, i<32 ----------
__global__ void rope_tables(float* __restrict__ cosT, float* __restrict__ sinT) {
    int idx = blockIdx.x * 256 + threadIdx.x;
    if (idx >= 256 * 32) return;
    int pos = idx >> 5, i = idx & 31;
    float theta = powf(10000.f, -(float)i * (1.f / 32.f));
    float ang = (float)pos * theta;
    float sv, cv;
    sincosf(ang, &sv, &cv);
    cosT[idx] = cv;
    sinT[idx] = sv;
}

// ---------- packw: fp32 -> bf16 weight pack ----------
__global__ void packw(const float* __restrict__ src, ushort_t* __restrict__ dst, int n) {
    const int i = (blockIdx.x * 256 + threadIdx.x) * 4;
    if (i < n) {
        float4 v = *(const float4*)(src + i);
        *(uint2*)(dst + i) = make_uint2(pk2(v.x, v.y), pk2(v.z, v.w));
    }
}

// ---------- lnpack_f: fp32 input -> LN bf16 out (+ optional raw bf16 pack) ----------
template<bool RAW>
__global__ void lnpack_f(const float* __restrict__ xin, const float* __restrict__ lng,
                         const float* __restrict__ lnbias, ushort_t* __restrict__ outb,
                         ushort_t* __restrict__ rawb) {
    const int lane = threadIdx.x & 63;
    const int w = threadIdx.x >> 6;
    const size_t tok = (size_t)blockIdx.x * 4 + w;
    const float* row = xin + tok * 512 + lane * 8;
    float4 a = *(const float4*)row;
    float4 b = *(const float4*)(row + 4);
    if (RAW) {
        uint4 rp = make_uint4(pk2(a.x, a.y), pk2(a.z, a.w), pk2(b.x, b.y), pk2(b.z, b.w));
        *(uint4*)(rawb + tok * 512 + lane * 8) = rp;
    }
    float s = a.x + a.y + a.z + a.w + b.x + b.y + b.z + b.w;
    float q = a.x*a.x + a.y*a.y + a.z*a.z + a.w*a.w + b.x*b.x + b.y*b.y + b.z*b.z + b.w*b.w;
    #pragma unroll
    for (int off = 32; off >= 1; off >>= 1) {
        s += __shfl_xor(s, off);
        q += __shfl_xor(q, off);
    }
    const float m = s * (1.f / 512.f);
    const float v = q * (1.f / 512.f) - m * m;
    const float rs = 1.f / sqrtf(v + 1e-12f);
    float4 gv0 = *(const float4*)(lng + lane * 8);
    float4 gv1 = *(const float4*)(lng + lane * 8 + 4);
    float4 bv0 = *(const float4*)(lnbias + lane * 8);
    float4 bv1 = *(const float4*)(lnbias + lane * 8 + 4);
    float o0 = (a.x - m) * rs * gv0.x + bv0.x;
    float o1 = (a.y - m) * rs * gv0.y + bv0.y;
    float o2 = (a.z - m) * rs * gv0.z + bv0.z;
    float o3 = (a.w - m) * rs * gv0.w + bv0.w;
    float o4 = (b.x - m) * rs * gv1.x + bv1.x;
    float o5 = (b.y - m) * rs * gv1.y + bv1.y;
    float o6 = (b.z - m) * rs * gv1.z + bv1.z;
    float o7 = (b.w - m) * rs * gv1.w + bv1.w;
    uint4 pk = make_uint4(pk2(o0, o1), pk2(o2, o3), pk2(o4, o5), pk2(o6, o7));
    *(uint4*)(outb + tok * 512 + lane * 8) = pk;
}

// ---------- lnpack_h: bf16 input -> LN bf16 out ----------
__global__ void lnpack_h(const ushort_t* __restrict__ xin, const float* __restrict__ lng,
                         const float* __restrict__ lnbias, ushort_t* __restrict__ outb) {
    const int lane = threadIdx.x & 63;
    const int w = threadIdx.x >> 6;
    const size_t tok = (size_t)blockIdx.x * 4 + w;
    const short8* rp = (const short8*)(xin + tok * 512 + lane * 8);
    const short8 r = rp[0];
    float x[8];
    #pragma unroll
    for (int jv = 0; jv < 8; ++jv) x[jv] = bf2f((ushort_t)r[jv]);
    float s = 0.f, q = 0.f;
    #pragma unroll
    for (int jv = 0; jv < 8; ++jv) { s += x[jv]; q += x[jv] * x[jv]; }
    #pragma unroll
    for (int off = 32; off >= 1; off >>= 1) {
        s += __shfl_xor(s, off);
        q += __shfl_xor(q, off);
    }
    const float m = s * (1.f / 512.f);
    const float v = q * (1.f / 512.f) - m * m;
    const float rs = 1.f / sqrtf(v + 1e-12f);
    float4 gv0 = *(const float4*)(lng + lane * 8);
    float4 gv1 = *(const float4*)(lng + lane * 8 + 4);
    float4 bv0 = *(const float4*)(lnbias + lane * 8);
    float4 bv1 = *(const float4*)(lnbias + lane * 8 + 4);
    float o[8];
    o[0] = (x[0] - m) * rs * gv0.x + bv0.x;
    o[1] = (x[1] - m) * rs * gv0.y + bv0.y;
    o[2] = (x[2] - m) * rs * gv0.z + bv0.z;
    o[3] = (x[3] - m) * rs * gv0.w + bv0.w;
    o[4] = (x[4] - m) * rs * gv1.x + bv1.x;
    o[5] = (x[5] - m) * rs * gv1.y + bv1.y;
    o[6] = (x[6] - m) * rs * gv1.z + bv1.z;
    o[7] = (x[7] - m) * rs * gv1.w + bv1.w;
    uint4 pk = make_uint4(pk2(o[0], o[1]), pk2(o[2], o[3]), pk2(o[4], o[5]), pk2(o[6], o[7]));
    *(uint4*)(outb + tok * 512 + lane * 8) = pk;
}

// ---------- fold_w: Weff[1536][512] bf16 = [U.Wq*0.125 | U.Wk | V^T.Wv] ----------
__global__ void fold_w(const float* __restrict__ Wq, const float* __restrict__ Wk,
                       const float* __restrict__ Wv, const float* __restrict__ U,
                       const float* __restrict__ V, ushort_t* __restrict__ Weff) {
    const int o = blockIdx.x;               // 0..1535
    const int proj = o >> 9, orow = o & 511;
    const int h = orow >> 6, d = orow & 63;
    const float* W = (proj == 0) ? Wq : (proj == 1) ? Wk : Wv;
    float coef[16];
    #pragma unroll
    for (int r = 0; r < 16; ++r)
        coef[r] = (proj < 2) ? U[h * 1024 + d * 16 + r] : V[h * 1024 + r * 64 + d];
    const float scale = (proj == 0) ? 0.125f : 1.f;   // fold 1/sqrt(64) into q
    for (int c = threadIdx.x; c < 512; c += 256) {
        float acc = 0.f;
        #pragma unroll
        for (int r = 0; r < 16; ++r) acc += coef[r] * W[(h * 16 + r) * 512 + c];
        Weff[(long)o * 512 + c] = f2bf(acc * scale);
    }
}

// ---------- gemm_qkv3: qkve[M][1536] = Ab[M][512] @ Weff^T ----------
// global_load_lds staging (round-12 lesson: reg-staged k-loop is latency-bound
// at every barrier's vmcnt(0) drain; m151: gload_lds 874 vs reg 646 TF).
// Linear LDS (required by gload_lds) + both-sides chunk swizzle c^=(row>>1)&3:
// applied to the per-lane GLOBAL source addr and to the ds_read chunk index
// (rule #21). 64B rows -> rows R,R+2 collide unswizzled; swizzle -> 2-way=free.
template<bool TIME>
__launch_bounds__(512)
__global__ void gemm_qkv3(const ushort_t* __restrict__ Ab, const ushort_t* __restrict__ Wb,
                          const float* __restrict__ cosT, const float* __restrict__ sinT,
                          ushort_t* __restrict__ Cout) {
    __shared__ __align__(16) char arena[24576];
    ushort_t* AsL = (ushort_t*)arena;          // 128 rows x 32 ushorts (8 KB)
    ushort_t* BsL = AsL + 4096;                // 256 rows x 32 ushorts (16 KB)
    ushort_t (*Ebuf)[72] = (ushort_t (*)[72])arena;   // 18432 B (aliases, post-loop)

    const int id = blockIdx.x;            // 0..3071
    const int xcd = id & 7;
    const int j = id >> 3;                // 0..383
    const int mBase = (xcd * 64 + j / 6) * 128;
    const int nBase = (j % 6) * 256;

    const int tid = threadIdx.x;
    const int lane = tid & 63;
    const int w8 = tid >> 6;              // wave 0..7

    f32x4 zero = {0.f, 0.f, 0.f, 0.f};
    f32x4 acc[4][4];
    #pragma unroll
    for (int a = 0; a < 4; ++a)
        #pragma unroll
        for (int b = 0; b < 4; ++b) acc[a][b] = zero;

    const int wr = w8 >> 2, wc = w8 & 3;
    const int l15 = lane & 15;
    const int g = lane >> 4;
    const int arw = wr * 64 + l15;
    const int brw = wc * 64 + l15;

    // per-lane swizzled source offsets for staging
    const int qa = (w8 << 6) + lane;             // A chunk id 0..511
    const int ra = qa >> 2;
    const int ca = (qa & 3) ^ ((ra >> 1) & 3);
    const long gsrcA = (long)(mBase + ra) * 512 + ca * 8;
    ushort_t* ldsA = AsL + (w8 << 9);            // wave-uniform

    int rb[2], cb[2];
    #pragma unroll
    for (int i = 0; i < 2; ++i) {
        const int qb = (w8 << 7) + (i << 6) + lane;   // B chunk id 0..1023
        rb[i] = qb >> 2;
        cb[i] = (qb & 3) ^ ((rb[i] >> 1) & 3);
    }

    for (int kt = 0; kt < 512; kt += 32) {
        __syncthreads();   // WAR: prev ds_reads done before overwrite
        gload16(Ab + gsrcA + kt, ldsA);
        #pragma unroll
        for (int i = 0; i < 2; ++i)
            gload16(Wb + (long)(nBase + rb[i]) * 512 + kt + cb[i] * 8,
                    BsL + (w8 << 10) + (i << 9));
        __syncthreads();   // RAW: loads drained (compiler emits vmcnt(0))

        short8 af[4], bf[4];
        #pragma unroll
        for (int mi = 0; mi < 4; ++mi) {
            const int R = arw + mi * 16;
            af[mi] = *(const short8*)(AsL + R * 32 + ((g ^ ((R >> 1) & 3)) * 8));
        }
        #pragma unroll
        for (int ni = 0; ni < 4; ++ni) {
            const int R = brw + ni * 16;
            bf[ni] = *(const short8*)(BsL + R * 32 + ((g ^ ((R >> 1) & 3)) * 8));
        }
        #pragma unroll
        for (int mi = 0; mi < 4; ++mi)
            #pragma unroll
            for (int ni = 0; ni < 4; ++ni)
                acc[mi][ni] = __builtin_amdgcn_mfma_f32_16x16x32_bf16(af[mi], bf[ni], acc[mi][ni], 0, 0, 0);
    }

    // ---- epilogue: 4 stages of 64-col slices through Ebuf (aliases arena) ----
    #pragma unroll 1
    for (int s = 0; s < 4; ++s) {
        __syncthreads();
        if (wc == s) {
            #pragma unroll
            for (int mi = 0; mi < 4; ++mi)
                #pragma unroll
                for (int ni = 0; ni < 4; ++ni)
                    #pragma unroll
                    for (int jj = 0; jj < 4; ++jj)
                        Ebuf[wr * 64 + mi * 16 + g * 4 + jj][ni * 16 + l15] =
                            f2bf(acc[mi][ni][jj]);
        }
        __syncthreads();
        #pragma unroll
        for (int it = 0; it < 2; ++it) {
            const int u = tid + it * 512;
            const int row = u >> 3, c8 = u & 7;
            short8 v8 = *(const short8*)&Ebuf[row][c8 * 8];
            const long grow = mBase + row;
            const int gcol = nBase + s * 64 + c8 * 8;
            ushort_t* dst = Cout + grow * 1536 + gcol;
            if (gcol < 1024) {   // rope q_exp / k_exp: pairs are in-lane
                const int pos = TIME ? ((int)(grow >> 8) & 63) : ((int)grow & 255);
                const float* cT = cosT + pos * 32 + c8 * 4;
                const float* sT = sinT + pos * 32 + c8 * 4;
                uint_t pkv[4];
                #pragma unroll
                for (int p = 0; p < 4; ++p) {
                    const float cc = cT[p], ss = sT[p];
                    const float re = bf2f((ushort_t)v8[2 * p]);
                    const float im = bf2f((ushort_t)v8[2 * p + 1]);
                    pkv[p] = pk2(re * cc - im * ss, re * ss + im * cc);
                }
                *(uint4*)dst = make_uint4(pkv[0], pkv[1], pkv[2], pkv[3]);
            } else {             // v_exp: straight copy
                *(short8*)dst = v8;
            }
        }
    }
}

// ---------- gemm256: all-bf16 128x256-tile GEMM (gate / proj paths) ----------
// Same global_load_lds staging + both-sides swizzle as gemm_qkv3.
// EPI 1 (gate, K=1024): g = sigmoid(acc+bias); out_bf16 = g*R1b + (1-g)*R2b
// EPI 2 (proj, K=512):  out_f32 = acc + bias + R1b
template<int EPI>
__launch_bounds__(512)
__global__ void gemm256(const ushort_t* __restrict__ A1b, const ushort_t* __restrict__ A2b,
                        const ushort_t* __restrict__ Bwb, void* __restrict__ Cout_,
                        const float* __restrict__ bias, const ushort_t* __restrict__ R1b,
                        const ushort_t* __restrict__ R2b) {
    constexpr int K = (EPI == 1) ? 1024 : 512;
    __shared__ __align__(16) char arena[24576];
    ushort_t* AsL = (ushort_t*)arena;          // 128 x 32 ushorts
    ushort_t* BsL = AsL + 4096;                // 256 x 32 ushorts

    const int id = blockIdx.x;            // 0..1023
    const int xcd = id & 7;
    const int j = id >> 3;                // 0..127
    const int mBase = (xcd * 64 + (j >> 1)) * 128;
    const int nBase = (j & 1) * 256;

    const int tid = threadIdx.x;
    const int lane = tid & 63;
    const int w8 = tid >> 6;

    f32x4 zero = {0.f, 0.f, 0.f, 0.f};
    f32x4 acc[4][4];
    #pragma unroll
    for (int a = 0; a < 4; ++a)
        #pragma unroll
        for (int b = 0; b < 4; ++b) acc[a][b] = zero;

    const int wr = w8 >> 2, wc = w8 & 3;
    const int l15 = lane & 15;
    const int g = lane >> 4;
    const int arw = wr * 64 + l15;
    const int brw = wc * 64 + l15;

    const int qa = (w8 << 6) + lane;
    const int ra = qa >> 2;
    const int ca = (qa & 3) ^ ((ra >> 1) & 3);
    ushort_t* ldsA = AsL + (w8 << 9);

    int rb[2], cb[2];
    #pragma unroll
    for (int i = 0; i < 2; ++i) {
        const int qb = (w8 << 7) + (i << 6) + lane;
        rb[i] = qb >> 2;
        cb[i] = (qb & 3) ^ ((rb[i] >> 1) & 3);
    }

    for (int kt = 0; kt < K; kt += 32) {
        const ushort_t* Abase = (EPI == 1 && kt >= 512) ? A2b : A1b;
        const int kcol = (EPI == 1 && kt >= 512) ? kt - 512 : kt;

        __syncthreads();
        gload16(Abase + (long)(mBase + ra) * 512 + kcol + ca * 8, ldsA);
        #pragma unroll
        for (int i = 0; i < 2; ++i)
            gload16(Bwb + (long)(nBase + rb[i]) * K + kt + cb[i] * 8,
                    BsL + (w8 << 10) + (i << 9));
        __syncthreads();

        short8 af[4], bf[4];
        #pragma unroll
        for (int mi = 0; mi < 4; ++mi) {
            const int R = arw + mi * 16;
            af[mi] = *(const short8*)(AsL + R * 32 + ((g ^ ((R >> 1) & 3)) * 8));
        }
        #pragma unroll
        for (int ni = 0; ni < 4; ++ni) {
            const int R = brw + ni * 16;
            bf[ni] = *(const short8*)(BsL + R * 32 + ((g ^ ((R >> 1) & 3)) * 8));
        }
        #pragma unroll
        for (int mi = 0; mi < 4; ++mi)
            #pragma unroll
            for (int ni = 0; ni < 4; ++ni)
                acc[mi][ni] = __builtin_amdgcn_mfma_f32_16x16x32_bf16(af[mi], bf[ni], acc[mi][ni], 0, 0, 0);
    }

    #pragma unroll
    for (int mi = 0; mi < 4; ++mi) {
        #pragma unroll
        for (int ni = 0; ni < 4; ++ni) {
            #pragma unroll
            for (int jj = 0; jj < 4; ++jj) {
                const long row = mBase + wr * 64 + mi * 16 + ((lane >> 4) << 2) + jj;
                const long col = nBase + wc * 64 + ni * 16 + l15;
                const long idx = row * 512 + col;
                const float v = acc[mi][ni][jj];
                if (EPI == 1) {
                    const float z = v + bias[col];
                    const float gg = 1.f / (1.f + __expf(-z));
                    const float o = gg * bf2f(R1b[idx]) + (1.f - gg) * bf2f(R2b[idx]);
                    ((ushort_t*)Cout_)[idx] = f2bf(o);
                } else {
                    ((float*)Cout_)[idx] = v + bias[col] + bf2f(R1b[idx]);
                }
            }
        }
    }
}

// ---------- attn3: pure flash MFMA attention on precomputed q/k/v_exp ----------
template<int SEQ, bool TIME>
__launch_bounds__(256)
__global__ void attn3(const ushort_t* __restrict__ qkve, ushort_t* __restrict__ xattn) {
    constexpr int NCH = SEQ / 64;
    constexpr int NQT = SEQ / 64;
    constexpr int NPART = 256 / SEQ;
    constexpr int DCH = 8 / NPART;

    __shared__ short Klds[SEQ][64];
    __shared__ short VTs[64][SEQ];
    __shared__ short Pw[4][16][40];

    const int bx = blockIdx.x;
    const int h = bx & 7;
    const int grp = bx >> 3;
    int tokBase, tokStride;
    if (TIME) {
        const int l = grp & (L_ - 1);
        const int b = grp >> 8;
        tokBase = b * T_ * L_ + l;
        tokStride = L_;
    } else {
        tokBase = grp * L_;
        tokStride = 1;
    }
    const int tid = threadIdx.x;
    const int lane = tid & 63;
    const int w = tid >> 6;

    {
        const int key = tid & (SEQ - 1);
        const int part = tid / SEQ;
        const long tok = tokBase + (long)key * tokStride;
        const ushort_t* kb = qkve + tok * 1536 + 512 + h * 64;
        const ushort_t* vb = qkve + tok * 1536 + 1024 + h * 64;
        #pragma unroll
        for (int c = 0; c < DCH; ++c) {
            const int chunk = part * DCH + c;
            const short8 kv = *(const short8*)(kb + chunk * 8);
            *(short8*)&Klds[key][(chunk ^ (key & 7)) * 8] = kv;
            const short8 vv = *(const short8*)(vb + chunk * 8);
            #pragma unroll
            for (int jx = 0; jx < 8; ++jx) {
                const int d = chunk * 8 + jx;
                VTs[d][(((key >> 3) ^ (d & 7)) * 8) + (key & 7)] = vv[jx];
            }
        }
    }
    __syncthreads();

    const int l15 = lane & 15;
    const int g = lane >> 4;

    #pragma unroll 1
    for (int qt = 0; qt < NQT; ++qt) {
        const int qbase = qt * 64 + w * 16;
        const long qtok = tokBase + (long)(qbase + l15) * tokStride;

        const ushort_t* qb = qkve + qtok * 1536 + h * 64;
        const short8 Qf0 = *(const short8*)(qb + g * 8);
        const short8 Qf1 = *(const short8*)(qb + 32 + g * 8);

        f32x4 O[4];
        #pragma unroll
        for (int nj = 0; nj < 4; ++nj) { f32x4 z = {0.f,0.f,0.f,0.f}; O[nj] = z; }
        float psum = 0.f;

        #pragma unroll 1
        for (int kb2 = 0; kb2 < NCH; ++kb2) {
            f32x4 S[4];
            #pragma unroll
            for (int f4 = 0; f4 < 4; ++f4) {
                const int row = kb2 * 64 + f4 * 16 + l15;
                const short8 a0 = *(const short8*)&Klds[row][((0 + g) ^ (l15 & 7)) * 8];
                const short8 a1 = *(const short8*)&Klds[row][((4 + g) ^ (l15 & 7)) * 8];
                f32x4 z = {0.f, 0.f, 0.f, 0.f};
                z = __builtin_amdgcn_mfma_f32_16x16x32_bf16(a0, Qf0, z, 0, 0, 0);
                S[f4] = __builtin_amdgcn_mfma_f32_16x16x32_bf16(a1, Qf1, z, 0, 0, 0);
            }
            #pragma unroll
            for (int f4 = 0; f4 < 4; ++f4)
                #pragma unroll
                for (int jj = 0; jj < 4; ++jj) {
                    const float p = __expf(fminf(S[f4][jj], 30.f));
                    S[f4][jj] = p;
                    psum += p;
                }

            #pragma unroll
            for (int sl = 0; sl < 2; ++sl) {
                #pragma unroll
                for (int h2 = 0; h2 < 2; ++h2) {
                    const int f4 = 2 * sl + h2;
                    short4v pv;
                    pv[0] = (short)f2bf(S[f4][0]);
                    pv[1] = (short)f2bf(S[f4][1]);
                    pv[2] = (short)f2bf(S[f4][2]);
                    pv[3] = (short)f2bf(S[f4][3]);
                    *(short4v*)&Pw[w][l15][h2 * 16 + 4 * g] = pv;
                }
                const short8 pa = *(const short8*)&Pw[w][l15][8 * g];
                const int sg = kb2 * 2 + sl;
                #pragma unroll
                for (int nj = 0; nj < 4; ++nj) {
                    const int row = nj * 16 + l15;
                    const short8 bv = *(const short8*)&VTs[row][((4 * sg + g) ^ (l15 & 7)) * 8];
                    O[nj] = __builtin_amdgcn_mfma_f32_16x16x32_bf16(pa, bv, O[nj], 0, 0, 0);
                }
            }
        }

        psum += __shfl_xor(psum, 16);
        psum += __shfl_xor(psum, 32);
        const float inv = 1.f / psum;
        #pragma unroll
        for (int jj = 0; jj < 4; ++jj) {
            const float invq = __shfl(inv, 4 * g + jj);
            const long row = tokBase + (long)(qbase + 4 * g + jj) * tokStride;
            ushort_t* op = xattn + row * 512 + h * 64 + l15;
            #pragma unroll
            for (int nj = 0; nj < 4; ++nj)
                op[nj * 16] = f2bf(O[nj][jj] * invq);
        }
    }
}

// ---------- launch ----------
extern "C" void kernel_launch(void* const* d_in, const int* in_sizes, int n_in,
                              void* d_out, int out_size, void* d_ws, size_t ws_size,
                              hipStream_t stream) {
    const float* x      = (const float*)d_in[0];
    const float* t_Wq   = (const float*)d_in[3];
    const float* t_Wk   = (const float*)d_in[4];
    const float* t_Wv   = (const float*)d_in[5];
    const float* t_U    = (const float*)d_in[6];
    const float* t_V    = (const float*)d_in[7];
    const float* a_Wq   = (const float*)d_in[8];
    const float* a_Wk   = (const float*)d_in[9];
    const float* a_Wv   = (const float*)d_in[10];
    const float* a_U    = (const float*)d_in[11];
    const float* a_V    = (const float*)d_in[12];
    const float* ln1_g  = (const float*)d_in[13];
    const float* ln1_b  = (const float*)d_in[14];
    const float* ln2_g  = (const float*)d_in[15];
    const float* ln2_b  = (const float*)d_in[16];
    const float* ln3_g  = (const float*)d_in[17];
    const float* ln3_b  = (const float*)d_in[18];
    const float* proj_W = (const float*)d_in[19];
    const float* proj_b = (const float*)d_in[20];
    const float* gt_W   = (const float*)d_in[21];
    const float* gt_b   = (const float*)d_in[22];
    const float* ga_W   = (const float*)d_in[23];
    const float* ga_b   = (const float*)d_in[24];
    float* out = (float*)d_out;

    const size_t NC = (size_t)NTOK * 512;
    ushort_t* xb   = (ushort_t*)d_ws;                  // bf16(x), 64MB — dead after gate A
    ushort_t* lnb  = xb + NC;                          // LN out / xatt bf16, 64MB
    ushort_t* resA = lnb + NC;                         // phase-A residual bf16, 64MB
    ushort_t* qkve = resA + NC;                        // q/k/v_exp bf16 [NTOK][1536], 192MB
    ushort_t* resB = qkve;                             // phase-B residual ALIASES qkve
    ushort_t* Weff = qkve + (size_t)NTOK * 1536;       // folded attn weights, 1.5MB
    ushort_t* gtWb = Weff + 1536 * 512;                // gate-A weights bf16, 1MB
    ushort_t* gaWb = gtWb + 512 * 1024;                // gate-B weights bf16, 1MB
    ushort_t* prWb = gaWb + 512 * 1024;                // proj weights bf16, 0.5MB
    float* cosT = (float*)(prWb + 512 * 512);
    float* sinT = cosT + 8192;
    ushort_t* xattb = lnb;

    rope_tables<<<32, 256, 0, stream>>>(cosT, sinT);
    packw<<<512, 256, 0, stream>>>(gt_W, gtWb, 512 * 1024);
    packw<<<512, 256, 0, stream>>>(ga_W, gaWb, 512 * 1024);
    packw<<<256, 256, 0, stream>>>(proj_W, prWb, 512 * 512);

    // ===== Phase A: time attention (seq=T, batch=B*L) =====
    fold_w<<<1536, 256, 0, stream>>>(t_Wq, t_Wk, t_Wv, t_U, t_V, Weff);
    lnpack_f<true><<<NTOK / 4, 256, 0, stream>>>(x, ln1_g, ln1_b, lnb, xb);
    gemm_qkv3<true><<<3072, 512, 0, stream>>>(lnb, Weff, cosT, sinT, qkve);
    attn3<64, true><<<B_ * L_ * H_, 256, 0, stream>>>(qkve, xattb);
    gemm256<1><<<1024, 512, 0, stream>>>(xb, xattb, gtWb, resA, gt_b, xb, xattb);

    // ===== Phase B: amino-acid attention (seq=L, batch=B*T) =====
    fold_w<<<1536, 256, 0, stream>>>(a_Wq, a_Wk, a_Wv, a_U, a_V, Weff);
    lnpack_h<<<NTOK / 4, 256, 0, stream>>>(resA, ln2_g, ln2_b, lnb);
    gemm_qkv3<false><<<3072, 512, 0, stream>>>(lnb, Weff, cosT, sinT, qkve);
    attn3<256, false><<<B_ * T_ * H_, 256, 0, stream>>>(qkve, xattb);
    gemm256<1><<<1024, 512, 0, stream>>>(resA, xattb, gaWb, resB, ga_b, resA, xattb);

    // ===== Phase C: output projection + residual =====
    lnpack_h<<<NTOK / 4, 256, 0, stream>>>(resB, ln3_g, ln3_b, lnb);
    gemm256<2><<<1024, 512, 0, stream>>>(lnb, nullptr, prWb, out, proj_b, resB, nullptr);
}

// Round 14
// 803.240 us; speedup vs baseline: 1.3468x; 1.0125x over previous
//
#include <hip/hip_runtime.h>

typedef __attribute__((ext_vector_type(8))) short short8;   // 8 bf16
typedef __attribute__((ext_vector_type(4))) short short4v;  // 4 bf16
typedef __attribute__((ext_vector_type(4))) float f32x4;    // MFMA acc
typedef unsigned short ushort_t;
typedef unsigned int uint_t;

#define B_ 4
#define T_ 64
#define L_ 256
#define C_ 512
#define H_ 8
#define NTOK 65536   // B*T*L

// ---------- helpers ----------
__device__ __forceinline__ ushort_t f2bf(float f) {
    uint_t u = __float_as_uint(f);
    u += 0x7FFFu + ((u >> 16) & 1u);   // RNE
    return (ushort_t)(u >> 16);
}
__device__ __forceinline__ float bf2f(ushort_t u) {
    return __uint_as_float((uint_t)u << 16);
}
__device__ __forceinline__ uint_t pk2(float a, float b) {
    return (uint_t)f2bf(a) | ((uint_t)f2bf(b) << 16);
}
// async global->LDS, 16B per lane; lds base must be wave-uniform (HW adds lane*16)
__device__ __forceinline__ void gload16(const ushort_t* __restrict__ g, ushort_t* l) {
    __builtin_amdgcn_global_load_lds(
        (const __attribute__((address_space(1))) void*)g,
        (__attribute__((address_space(3))) void*)l,
        16, 0, 0);
}

// ---------- RoPE tables: cos/sin[pos][i], pos<256, i<32 ----------
__global__ void rope_tables(float* __restrict__ cosT, float* __restrict__ sinT) {
    int idx = blockIdx.x * 256 + threadIdx.x;
    if (idx >= 256 * 32) return;
    int pos = idx >> 5, i = idx & 31;
    float theta = powf(10000.f, -(float)i * (1.f / 32.f));
    float ang = (float)pos * theta;
    float sv, cv;
    sincosf(ang, &sv, &cv);
    cosT[idx] = cv;
    sinT[idx] = sv;
}

// ---------- packw: fp32 -> bf16 weight pack ----------
__global__ void packw(const float* __restrict__ src, ushort_t* __restrict__ dst, int n) {
    const int i = (blockIdx.x * 256 + threadIdx.x) * 4;
    if (i < n) {
        float4 v = *(const float4*)(src + i);
        *(uint2*)(dst + i) = make_uint2(pk2(v.x, v.y), pk2(v.z, v.w));
    }
}

// ---------- lnpack_f: fp32 input -> LN bf16 out (+ optional raw bf16 pack) ----------
template<bool RAW>
__global__ void lnpack_f(const float* __restrict__ xin, const float* __restrict__ lng,
                         const float* __restrict__ lnbias, ushort_t* __restrict__ outb,
                         ushort_t* __restrict__ rawb) {
    const int lane = threadIdx.x & 63;
    const int w = threadIdx.x >> 6;
    const size_t tok = (size_t)blockIdx.x * 4 + w;
    const float* row = xin + tok * 512 + lane * 8;
    float4 a = *(const float4*)row;
    float4 b = *(const float4*)(row + 4);
    if (RAW) {
        uint4 rp = make_uint4(pk2(a.x, a.y), pk2(a.z, a.w), pk2(b.x, b.y), pk2(b.z, b.w));
        *(uint4*)(rawb + tok * 512 + lane * 8) = rp;
    }
    float s = a.x + a.y + a.z + a.w + b.x + b.y + b.z + b.w;
    float q = a.x*a.x + a.y*a.y + a.z*a.z + a.w*a.w + b.x*b.x + b.y*b.y + b.z*b.z + b.w*b.w;
    #pragma unroll
    for (int off = 32; off >= 1; off >>= 1) {
        s += __shfl_xor(s, off);
        q += __shfl_xor(q, off);
    }
    const float m = s * (1.f / 512.f);
    const float v = q * (1.f / 512.f) - m * m;
    const float rs = 1.f / sqrtf(v + 1e-12f);
    float4 gv0 = *(const float4*)(lng + lane * 8);
    float4 gv1 = *(const float4*)(lng + lane * 8 + 4);
    float4 bv0 = *(const float4*)(lnbias + lane * 8);
    float4 bv1 = *(const float4*)(lnbias + lane * 8 + 4);
    float o0 = (a.x - m) * rs * gv0.x + bv0.x;
    float o1 = (a.y - m) * rs * gv0.y + bv0.y;
    float o2 = (a.z - m) * rs * gv0.z + bv0.z;
    float o3 = (a.w - m) * rs * gv0.w + bv0.w;
    float o4 = (b.x - m) * rs * gv1.x + bv1.x;
    float o5 = (b.y - m) * rs * gv1.y + bv1.y;
    float o6 = (b.z - m) * rs * gv1.z + bv1.z;
    float o7 = (b.w - m) * rs * gv1.w + bv1.w;
    uint4 pk = make_uint4(pk2(o0, o1), pk2(o2, o3), pk2(o4, o5), pk2(o6, o7));
    *(uint4*)(outb + tok * 512 + lane * 8) = pk;
}

// ---------- lnpack_h: bf16 input -> LN bf16 out ----------
__global__ void lnpack_h(const ushort_t* __restrict__ xin, const float* __restrict__ lng,
                         const float* __restrict__ lnbias, ushort_t* __restrict__ outb) {
    const int lane = threadIdx.x & 63;
    const int w = threadIdx.x >> 6;
    const size_t tok = (size_t)blockIdx.x * 4 + w;
    const short8* rp = (const short8*)(xin + tok * 512 + lane * 8);
    const short8 r = rp[0];
    float x[8];
    #pragma unroll
    for (int jv = 0; jv < 8; ++jv) x[jv] = bf2f((ushort_t)r[jv]);
    float s = 0.f, q = 0.f;
    #pragma unroll
    for (int jv = 0; jv < 8; ++jv) { s += x[jv]; q += x[jv] * x[jv]; }
    #pragma unroll
    for (int off = 32; off >= 1; off >>= 1) {
        s += __shfl_xor(s, off);
        q += __shfl_xor(q, off);
    }
    const float m = s * (1.f / 512.f);
    const float v = q * (1.f / 512.f) - m * m;
    const float rs = 1.f / sqrtf(v + 1e-12f);
    float4 gv0 = *(const float4*)(lng + lane * 8);
    float4 gv1 = *(const float4*)(lng + lane * 8 + 4);
    float4 bv0 = *(const float4*)(lnbias + lane * 8);
    float4 bv1 = *(const float4*)(lnbias + lane * 8 + 4);
    float o[8];
    o[0] = (x[0] - m) * rs * gv0.x + bv0.x;
    o[1] = (x[1] - m) * rs * gv0.y + bv0.y;
    o[2] = (x[2] - m) * rs * gv0.z + bv0.z;
    o[3] = (x[3] - m) * rs * gv0.w + bv0.w;
    o[4] = (x[4] - m) * rs * gv1.x + bv1.x;
    o[5] = (x[5] - m) * rs * gv1.y + bv1.y;
    o[6] = (x[6] - m) * rs * gv1.z + bv1.z;
    o[7] = (x[7] - m) * rs * gv1.w + bv1.w;
    uint4 pk = make_uint4(pk2(o[0], o[1]), pk2(o[2], o[3]), pk2(o[4], o[5]), pk2(o[6], o[7]));
    *(uint4*)(outb + tok * 512 + lane * 8) = pk;
}

// ---------- fold_w: Weff[1536][512] bf16 = [U.Wq*0.125 | U.Wk | V^T.Wv] ----------
__global__ void fold_w(const float* __restrict__ Wq, const float* __restrict__ Wk,
                       const float* __restrict__ Wv, const float* __restrict__ U,
                       const float* __restrict__ V, ushort_t* __restrict__ Weff) {
    const int o = blockIdx.x;               // 0..1535
    const int proj = o >> 9, orow = o & 511;
    const int h = orow >> 6, d = orow & 63;
    const float* W = (proj == 0) ? Wq : (proj == 1) ? Wk : Wv;
    float coef[16];
    #pragma unroll
    for (int r = 0; r < 16; ++r)
        coef[r] = (proj < 2) ? U[h * 1024 + d * 16 + r] : V[h * 1024 + r * 64 + d];
    const float scale = (proj == 0) ? 0.125f : 1.f;   // fold 1/sqrt(64) into q
    for (int c = threadIdx.x; c < 512; c += 256) {
        float acc = 0.f;
        #pragma unroll
        for (int r = 0; r < 16; ++r) acc += coef[r] * W[(h * 16 + r) * 512 + c];
        Weff[(long)o * 512 + c] = f2bf(acc * scale);
    }
}

// ---------- gemm_qkv3: qkve[M][1536] = Ab[M][512] @ Weff^T ----------
// Double-buffered global_load_lds with PREFETCH (T3 minimal 2-phase): each
// K-step issues next-tile loads into buf^1 BEFORE computing buf, one barrier
// per step — the pre-barrier vmcnt(0) now waits on loads that had the whole
// MFMA phase to fly (round-13 lesson: stage->drain->compute exposed full load
// latency 16x/block; MfmaUtil 27% with nothing saturated).
// Linear LDS + both-sides chunk swizzle c^=(row>>1)&3 (rule #21).
template<bool TIME>
__launch_bounds__(512)
__global__ void gemm_qkv3(const ushort_t* __restrict__ Ab, const ushort_t* __restrict__ Wb,
                          const float* __restrict__ cosT, const float* __restrict__ sinT,
                          ushort_t* __restrict__ Cout) {
    __shared__ __align__(16) char arena[49152];       // 2 x 24576 (A 8KB + B 16KB)
    ushort_t (*Ebuf)[72] = (ushort_t (*)[72])arena;   // 18432 B (aliases buf0, post-loop)

    const int id = blockIdx.x;            // 0..3071
    const int xcd = id & 7;
    const int j = id >> 3;                // 0..383
    const int mBase = (xcd * 64 + j / 6) * 128;
    const int nBase = (j % 6) * 256;

    const int tid = threadIdx.x;
    const int lane = tid & 63;
    const int w8 = tid >> 6;              // wave 0..7

    f32x4 zero = {0.f, 0.f, 0.f, 0.f};
    f32x4 acc[4][4];
    #pragma unroll
    for (int a = 0; a < 4; ++a)
        #pragma unroll
        for (int b = 0; b < 4; ++b) acc[a][b] = zero;

    const int wr = w8 >> 2, wc = w8 & 3;
    const int l15 = lane & 15;
    const int g = lane >> 4;
    const int arw = wr * 64 + l15;
    const int brw = wc * 64 + l15;

    // per-lane swizzled source addresses for staging
    const int qa = (w8 << 6) + lane;             // A chunk id 0..511
    const int ra = qa >> 2;
    const int ca = (qa & 3) ^ ((ra >> 1) & 3);
    const ushort_t* srcA = Ab + (long)(mBase + ra) * 512 + ca * 8;

    const ushort_t* srcB[2];
    #pragma unroll
    for (int i = 0; i < 2; ++i) {
        const int qb = (w8 << 7) + (i << 6) + lane;   // B chunk id 0..1023
        const int rbv = qb >> 2;
        const int cbv = (qb & 3) ^ ((rbv >> 1) & 3);
        srcB[i] = Wb + (long)(nBase + rbv) * 512 + cbv * 8;
    }

    // prologue: stage kt=0 into buf0
    {
        ushort_t* base = (ushort_t*)arena;
        gload16(srcA, base + (w8 << 9));
        gload16(srcB[0], base + 4096 + (w8 << 10));
        gload16(srcB[1], base + 4096 + (w8 << 10) + 512);
    }
    asm volatile("s_waitcnt vmcnt(0)" ::: "memory");
    __syncthreads();

    #pragma unroll 1
    for (int kt = 0; kt < 512; kt += 32) {
        const int cur = (kt >> 5) & 1;
        // prefetch next tile into the other buffer (flies during MFMA below)
        if (kt + 32 < 512) {
            ushort_t* nb = (ushort_t*)(arena + (cur ^ 1) * 24576);
            gload16(srcA + kt + 32, nb + (w8 << 9));
            gload16(srcB[0] + kt + 32, nb + 4096 + (w8 << 10));
            gload16(srcB[1] + kt + 32, nb + 4096 + (w8 << 10) + 512);
        }
        ushort_t* AsL = (ushort_t*)(arena + cur * 24576);
        ushort_t* BsL = AsL + 4096;

        short8 af[4], bf[4];
        #pragma unroll
        for (int mi = 0; mi < 4; ++mi) {
            const int R = arw + mi * 16;
            af[mi] = *(const short8*)(AsL + R * 32 + ((g ^ ((R >> 1) & 3)) * 8));
        }
        #pragma unroll
        for (int ni = 0; ni < 4; ++ni) {
            const int R = brw + ni * 16;
            bf[ni] = *(const short8*)(BsL + R * 32 + ((g ^ ((R >> 1) & 3)) * 8));
        }
        #pragma unroll
        for (int mi = 0; mi < 4; ++mi)
            #pragma unroll
            for (int ni = 0; ni < 4; ++ni)
                acc[mi][ni] = __builtin_amdgcn_mfma_f32_16x16x32_bf16(af[mi], bf[ni], acc[mi][ni], 0, 0, 0);

        __syncthreads();   // vmcnt(0)+lgkmcnt(0) drain: prefetched loads had the
                           // whole MFMA phase in flight; WAR on buf[cur] safe.
    }

    // ---- epilogue: 4 stages of 64-col slices through Ebuf (aliases buf0) ----
    #pragma unroll 1
    for (int s = 0; s < 4; ++s) {
        __syncthreads();
        if (wc == s) {
            #pragma unroll
            for (int mi = 0; mi < 4; ++mi)
                #pragma unroll
                for (int ni = 0; ni < 4; ++ni)
                    #pragma unroll
                    for (int jj = 0; jj < 4; ++jj)
                        Ebuf[wr * 64 + mi * 16 + g * 4 + jj][ni * 16 + l15] =
                            f2bf(acc[mi][ni][jj]);
        }
        __syncthreads();
        #pragma unroll
        for (int it = 0; it < 2; ++it) {
            const int u = tid + it * 512;
            const int row = u >> 3, c8 = u & 7;
            short8 v8 = *(const short8*)&Ebuf[row][c8 * 8];
            const long grow = mBase + row;
            const int gcol = nBase + s * 64 + c8 * 8;
            ushort_t* dst = Cout + grow * 1536 + gcol;
            if (gcol < 1024) {   // rope q_exp / k_exp: pairs are in-lane
                const int pos = TIME ? ((int)(grow >> 8) & 63) : ((int)grow & 255);
                const float* cT = cosT + pos * 32 + c8 * 4;
                const float* sT = sinT + pos * 32 + c8 * 4;
                uint_t pkv[4];
                #pragma unroll
                for (int p = 0; p < 4; ++p) {
                    const float cc = cT[p], ss = sT[p];
                    const float re = bf2f((ushort_t)v8[2 * p]);
                    const float im = bf2f((ushort_t)v8[2 * p + 1]);
                    pkv[p] = pk2(re * cc - im * ss, re * ss + im * cc);
                }
                *(uint4*)dst = make_uint4(pkv[0], pkv[1], pkv[2], pkv[3]);
            } else {             // v_exp: straight copy
                *(short8*)dst = v8;
            }
        }
    }
}

// ---------- gemm256: all-bf16 128x256-tile GEMM (gate / proj paths) ----------
// Same 2-phase prefetch pipeline as gemm_qkv3.
// EPI 1 (gate, K=1024): g = sigmoid(acc+bias); out_bf16 = g*R1b + (1-g)*R2b
// EPI 2 (proj, K=512):  out_f32 = acc + bias + R1b
template<int EPI>
__launch_bounds__(512)
__global__ void gemm256(const ushort_t* __restrict__ A1b, const ushort_t* __restrict__ A2b,
                        const ushort_t* __restrict__ Bwb, void* __restrict__ Cout_,
                        const float* __restrict__ bias, const ushort_t* __restrict__ R1b,
                        const ushort_t* __restrict__ R2b) {
    constexpr int K = (EPI == 1) ? 1024 : 512;
    __shared__ __align__(16) char arena[49152];

    const int id = blockIdx.x;            // 0..1023
    const int xcd = id & 7;
    const int j = id >> 3;                // 0..127
    const int mBase = (xcd * 64 + (j >> 1)) * 128;
    const int nBase = (j & 1) * 256;

    const int tid = threadIdx.x;
    const int lane = tid & 63;
    const int w8 = tid >> 6;

    f32x4 zero = {0.f, 0.f, 0.f, 0.f};
    f32x4 acc[4][4];
    #pragma unroll
    for (int a = 0; a < 4; ++a)
        #pragma unroll
        for (int b = 0; b < 4; ++b) acc[a][b] = zero;

    const int wr = w8 >> 2, wc = w8 & 3;
    const int l15 = lane & 15;
    const int g = lane >> 4;
    const int arw = wr * 64 + l15;
    const int brw = wc * 64 + l15;

    const int qa = (w8 << 6) + lane;
    const int ra = qa >> 2;
    const int ca = (qa & 3) ^ ((ra >> 1) & 3);
    const long offA = (long)(mBase + ra) * 512 + ca * 8;

    const ushort_t* srcB[2];
    #pragma unroll
    for (int i = 0; i < 2; ++i) {
        const int qb = (w8 << 7) + (i << 6) + lane;
        const int rbv = qb >> 2;
        const int cbv = (qb & 3) ^ ((rbv >> 1) & 3);
        srcB[i] = Bwb + (long)(nBase + rbv) * K + cbv * 8;
    }

    // prologue: stage kt=0 into buf0
    {
        ushort_t* base = (ushort_t*)arena;
        gload16(A1b + offA, base + (w8 << 9));
        gload16(srcB[0], base + 4096 + (w8 << 10));
        gload16(srcB[1], base + 4096 + (w8 << 10) + 512);
    }
    asm volatile("s_waitcnt vmcnt(0)" ::: "memory");
    __syncthreads();

    #pragma unroll 1
    for (int kt = 0; kt < K; kt += 32) {
        const int cur = (kt >> 5) & 1;
        if (kt + 32 < K) {
            const int kn = kt + 32;
            const ushort_t* an = (EPI == 1 && kn >= 512) ? (A2b + offA + (kn - 512))
                                                         : (A1b + offA + kn);
            ushort_t* nb = (ushort_t*)(arena + (cur ^ 1) * 24576);
            gload16(an, nb + (w8 << 9));
            gload16(srcB[0] + kn, nb + 4096 + (w8 << 10));
            gload16(srcB[1] + kn, nb + 4096 + (w8 << 10) + 512);
        }
        ushort_t* AsL = (ushort_t*)(arena + cur * 24576);
        ushort_t* BsL = AsL + 4096;

        short8 af[4], bf[4];
        #pragma unroll
        for (int mi = 0; mi < 4; ++mi) {
            const int R = arw + mi * 16;
            af[mi] = *(const short8*)(AsL + R * 32 + ((g ^ ((R >> 1) & 3)) * 8));
        }
        #pragma unroll
        for (int ni = 0; ni < 4; ++ni) {
            const int R = brw + ni * 16;
            bf[ni] = *(const short8*)(BsL + R * 32 + ((g ^ ((R >> 1) & 3)) * 8));
        }
        #pragma unroll
        for (int mi = 0; mi < 4; ++mi)
            #pragma unroll
            for (int ni = 0; ni < 4; ++ni)
                acc[mi][ni] = __builtin_amdgcn_mfma_f32_16x16x32_bf16(af[mi], bf[ni], acc[mi][ni], 0, 0, 0);

        __syncthreads();
    }

    #pragma unroll
    for (int mi = 0; mi < 4; ++mi) {
        #pragma unroll
        for (int ni = 0; ni < 4; ++ni) {
            #pragma unroll
            for (int jj = 0; jj < 4; ++jj) {
                const long row = mBase + wr * 64 + mi * 16 + ((lane >> 4) << 2) + jj;
                const long col = nBase + wc * 64 + ni * 16 + l15;
                const long idx = row * 512 + col;
                const float v = acc[mi][ni][jj];
                if (EPI == 1) {
                    const float z = v + bias[col];
                    const float gg = 1.f / (1.f + __expf(-z));
                    const float o = gg * bf2f(R1b[idx]) + (1.f - gg) * bf2f(R2b[idx]);
                    ((ushort_t*)Cout_)[idx] = f2bf(o);
                } else {
                    ((float*)Cout_)[idx] = v + bias[col] + bf2f(R1b[idx]);
                }
            }
        }
    }
}

// ---------- attn3: pure flash MFMA attention on precomputed q/k/v_exp ----------
template<int SEQ, bool TIME>
__launch_bounds__(256)
__global__ void attn3(const ushort_t* __restrict__ qkve, ushort_t* __restrict__ xattn) {
    constexpr int NCH = SEQ / 64;
    constexpr int NQT = SEQ / 64;
    constexpr int NPART = 256 / SEQ;
    constexpr int DCH = 8 / NPART;

    __shared__ short Klds[SEQ][64];
    __shared__ short VTs[64][SEQ];
    __shared__ short Pw[4][16][40];

    const int bx = blockIdx.x;
    const int h = bx & 7;
    const int grp = bx >> 3;
    int tokBase, tokStride;
    if (TIME) {
        const int l = grp & (L_ - 1);
        const int b = grp >> 8;
        tokBase = b * T_ * L_ + l;
        tokStride = L_;
    } else {
        tokBase = grp * L_;
        tokStride = 1;
    }
    const int tid = threadIdx.x;
    const int lane = tid & 63;
    const int w = tid >> 6;

    {
        const int key = tid & (SEQ - 1);
        const int part = tid / SEQ;
        const long tok = tokBase + (long)key * tokStride;
        const ushort_t* kb = qkve + tok * 1536 + 512 + h * 64;
        const ushort_t* vb = qkve + tok * 1536 + 1024 + h * 64;
        #pragma unroll
        for (int c = 0; c < DCH; ++c) {
            const int chunk = part * DCH + c;
            const short8 kv = *(const short8*)(kb + chunk * 8);
            *(short8*)&Klds[key][(chunk ^ (key & 7)) * 8] = kv;
            const short8 vv = *(const short8*)(vb + chunk * 8);
            #pragma unroll
            for (int jx = 0; jx < 8; ++jx) {
                const int d = chunk * 8 + jx;
                VTs[d][(((key >> 3) ^ (d & 7)) * 8) + (key & 7)] = vv[jx];
            }
        }
    }
    __syncthreads();

    const int l15 = lane & 15;
    const int g = lane >> 4;

    #pragma unroll 1
    for (int qt = 0; qt < NQT; ++qt) {
        const int qbase = qt * 64 + w * 16;
        const long qtok = tokBase + (long)(qbase + l15) * tokStride;

        const ushort_t* qb = qkve + qtok * 1536 + h * 64;
        const short8 Qf0 = *(const short8*)(qb + g * 8);
        const short8 Qf1 = *(const short8*)(qb + 32 + g * 8);

        f32x4 O[4];
        #pragma unroll
        for (int nj = 0; nj < 4; ++nj) { f32x4 z = {0.f,0.f,0.f,0.f}; O[nj] = z; }
        float psum = 0.f;

        #pragma unroll 1
        for (int kb2 = 0; kb2 < NCH; ++kb2) {
            f32x4 S[4];
            #pragma unroll
            for (int f4 = 0; f4 < 4; ++f4) {
                const int row = kb2 * 64 + f4 * 16 + l15;
                const short8 a0 = *(const short8*)&Klds[row][((0 + g) ^ (l15 & 7)) * 8];
                const short8 a1 = *(const short8*)&Klds[row][((4 + g) ^ (l15 & 7)) * 8];
                f32x4 z = {0.f, 0.f, 0.f, 0.f};
                z = __builtin_amdgcn_mfma_f32_16x16x32_bf16(a0, Qf0, z, 0, 0, 0);
                S[f4] = __builtin_amdgcn_mfma_f32_16x16x32_bf16(a1, Qf1, z, 0, 0, 0);
            }
            #pragma unroll
            for (int f4 = 0; f4 < 4; ++f4)
                #pragma unroll
                for (int jj = 0; jj < 4; ++jj) {
                    const float p = __expf(fminf(S[f4][jj], 30.f));
                    S[f4][jj] = p;
                    psum += p;
                }

            #pragma unroll
            for (int sl = 0; sl < 2; ++sl) {
                #pragma unroll
                for (int h2 = 0; h2 < 2; ++h2) {
                    const int f4 = 2 * sl + h2;
                    short4v pv;
                    pv[0] = (short)f2bf(S[f4][0]);
                    pv[1] = (short)f2bf(S[f4][1]);
                    pv[2] = (short)f2bf(S[f4][2]);
                    pv[3] = (short)f2bf(S[f4][3]);
                    *(short4v*)&Pw[w][l15][h2 * 16 + 4 * g] = pv;
                }
                const short8 pa = *(const short8*)&Pw[w][l15][8 * g];
                const int sg = kb2 * 2 + sl;
                #pragma unroll
                for (int nj = 0; nj < 4; ++nj) {
                    const int row = nj * 16 + l15;
                    const short8 bv = *(const short8*)&VTs[row][((4 * sg + g) ^ (l15 & 7)) * 8];
                    O[nj] = __builtin_amdgcn_mfma_f32_16x16x32_bf16(pa, bv, O[nj], 0, 0, 0);
                }
            }
        }

        psum += __shfl_xor(psum, 16);
        psum += __shfl_xor(psum, 32);
        const float inv = 1.f / psum;
        #pragma unroll
        for (int jj = 0; jj < 4; ++jj) {
            const float invq = __shfl(inv, 4 * g + jj);
            const long row = tokBase + (long)(qbase + 4 * g + jj) * tokStride;
            ushort_t* op = xattn + row * 512 + h * 64 + l15;
            #pragma unroll
            for (int nj = 0; nj < 4; ++nj)
                op[nj * 16] = f2bf(O[nj][jj] * invq);
        }
    }
}

// ---------- launch ----------
extern "C" void kernel_launch(void* const* d_in, const int* in_sizes, int n_in,
                              void* d_out, int out_size, void* d_ws, size_t ws_size,
                              hipStream_t stream) {
    const float* x      = (const float*)d_in[0];
    const float* t_Wq   = (const float*)d_in[3];
    const float* t_Wk   = (const float*)d_in[4];
    const float* t_Wv   = (const float*)d_in[5];
    const float* t_U    = (const float*)d_in[6];
    const float* t_V    = (const float*)d_in[7];
    const float* a_Wq   = (const float*)d_in[8];
    const float* a_Wk   = (const float*)d_in[9];
    const float* a_Wv   = (const float*)d_in[10];
    const float* a_U    = (const float*)d_in[11];
    const float* a_V    = (const float*)d_in[12];
    const float* ln1_g  = (const float*)d_in[13];
    const float* ln1_b  = (const float*)d_in[14];
    const float* ln2_g  = (const float*)d_in[15];
    const float* ln2_b  = (const float*)d_in[16];
    const float* ln3_g  = (const float*)d_in[17];
    const float* ln3_b  = (const float*)d_in[18];
    const float* proj_W = (const float*)d_in[19];
    const float* proj_b = (const float*)d_in[20];
    const float* gt_W   = (const float*)d_in[21];
    const float* gt_b   = (const float*)d_in[22];
    const float* ga_W   = (const float*)d_in[23];
    const float* ga_b   = (const float*)d_in[24];
    float* out = (float*)d_out;

    const size_t NC = (size_t)NTOK * 512;
    ushort_t* xb   = (ushort_t*)d_ws;                  // bf16(x), 64MB — dead after gate A
    ushort_t* lnb  = xb + NC;                          // LN out / xatt bf16, 64MB
    ushort_t* resA = lnb + NC;                         // phase-A residual bf16, 64MB
    ushort_t* qkve = resA + NC;                        // q/k/v_exp bf16 [NTOK][1536], 192MB
    ushort_t* resB = qkve;                             // phase-B residual ALIASES qkve
    ushort_t* Weff = qkve + (size_t)NTOK * 1536;       // folded attn weights, 1.5MB
    ushort_t* gtWb = Weff + 1536 * 512;                // gate-A weights bf16, 1MB
    ushort_t* gaWb = gtWb + 512 * 1024;                // gate-B weights bf16, 1MB
    ushort_t* prWb = gaWb + 512 * 1024;                // proj weights bf16, 0.5MB
    float* cosT = (float*)(prWb + 512 * 512);
    float* sinT = cosT + 8192;
    ushort_t* xattb = lnb;

    rope_tables<<<32, 256, 0, stream>>>(cosT, sinT);
    packw<<<512, 256, 0, stream>>>(gt_W, gtWb, 512 * 1024);
    packw<<<512, 256, 0, stream>>>(ga_W, gaWb, 512 * 1024);
    packw<<<256, 256, 0, stream>>>(proj_W, prWb, 512 * 512);

    // ===== Phase A: time attention (seq=T, batch=B*L) =====
    fold_w<<<1536, 256, 0, stream>>>(t_Wq, t_Wk, t_Wv, t_U, t_V, Weff);
    lnpack_f<true><<<NTOK / 4, 256, 0, stream>>>(x, ln1_g, ln1_b, lnb, xb);
    gemm_qkv3<true><<<3072, 512, 0, stream>>>(lnb, Weff, cosT, sinT, qkve);
    attn3<64, true><<<B_ * L_ * H_, 256, 0, stream>>>(qkve, xattb);
    gemm256<1><<<1024, 512, 0, stream>>>(xb, xattb, gtWb, resA, gt_b, xb, xattb);

    // ===== Phase B: amino-acid attention (seq=L, batch=B*T) =====
    fold_w<<<1536, 256, 0, stream>>>(a_Wq, a_Wk, a_Wv, a_U, a_V, Weff);
    lnpack_h<<<NTOK / 4, 256, 0, stream>>>(resA, ln2_g, ln2_b, lnb);
    gemm_qkv3<false><<<3072, 512, 0, stream>>>(lnb, Weff, cosT, sinT, qkve);
    attn3<256, false><<<B_ * T_ * H_, 256, 0, stream>>>(qkve, xattb);
    gemm256<1><<<1024, 512, 0, stream>>>(resA, xattb, gaWb, resB, ga_b, resA, xattb);

    // ===== Phase C: output projection + residual =====
    lnpack_h<<<NTOK / 4, 256, 0, stream>>>(resB, ln3_g, ln3_b, lnb);
    gemm256<2><<<1024, 512, 0, stream>>>(lnb, nullptr, prWb, out, proj_b, resB, nullptr);
}

// Round 15
// 760.673 us; speedup vs baseline: 1.4222x; 1.0560x over previous
//
#include <hip/hip_runtime.h>

typedef __attribute__((ext_vector_type(8))) short short8;   // 8 bf16
typedef __attribute__((ext_vector_type(4))) short short4v;  // 4 bf16
typedef __attribute__((ext_vector_type(4))) float f32x4;    // MFMA acc
typedef unsigned short ushort_t;
typedef unsigned int uint_t;

#define B_ 4
#define T_ 64
#define L_ 256
#define C_ 512
#define H_ 8
#define NTOK 65536   // B*T*L
#define QKV_W 1280   // q_exp(512) | k_exp(512) | v_low(128) | pad(128)

// ---------- helpers ----------
__device__ __forceinline__ ushort_t f2bf(float f) {
    uint_t u = __float_as_uint(f);
    u += 0x7FFFu + ((u >> 16) & 1u);   // RNE
    return (ushort_t)(u >> 16);
}
__device__ __forceinline__ float bf2f(ushort_t u) {
    return __uint_as_float((uint_t)u << 16);
}
__device__ __forceinline__ uint_t pk2(float a, float b) {
    return (uint_t)f2bf(a) | ((uint_t)f2bf(b) << 16);
}
// async global->LDS, 16B per lane; lds base must be wave-uniform (HW adds lane*16)
__device__ __forceinline__ void gload16(const ushort_t* __restrict__ g, ushort_t* l) {
    __builtin_amdgcn_global_load_lds(
        (const __attribute__((address_space(1))) void*)g,
        (__attribute__((address_space(3))) void*)l,
        16, 0, 0);
}

// ---------- RoPE tables: cos/sin[pos][i], pos<256, i<32 ----------
__global__ void rope_tables(float* __restrict__ cosT, float* __restrict__ sinT) {
    int idx = blockIdx.x * 256 + threadIdx.x;
    if (idx >= 256 * 32) return;
    int pos = idx >> 5, i = idx & 31;
    float theta = powf(10000.f, -(float)i * (1.f / 32.f));
    float ang = (float)pos * theta;
    float sv, cv;
    sincosf(ang, &sv, &cv);
    cosT[idx] = cv;
    sinT[idx] = sv;
}

// ---------- packw: fp32 -> bf16 weight pack ----------
__global__ void packw(const float* __restrict__ src, ushort_t* __restrict__ dst, int n) {
    const int i = (blockIdx.x * 256 + threadIdx.x) * 4;
    if (i < n) {
        float4 v = *(const float4*)(src + i);
        *(uint2*)(dst + i) = make_uint2(pk2(v.x, v.y), pk2(v.z, v.w));
    }
}

// ---------- lnpack_f: fp32 input -> LN bf16 out (+ optional raw bf16 pack) ----------
template<bool RAW>
__global__ void lnpack_f(const float* __restrict__ xin, const float* __restrict__ lng,
                         const float* __restrict__ lnbias, ushort_t* __restrict__ outb,
                         ushort_t* __restrict__ rawb) {
    const int lane = threadIdx.x & 63;
    const int w = threadIdx.x >> 6;
    const size_t tok = (size_t)blockIdx.x * 4 + w;
    const float* row = xin + tok * 512 + lane * 8;
    float4 a = *(const float4*)row;
    float4 b = *(const float4*)(row + 4);
    if (RAW) {
        uint4 rp = make_uint4(pk2(a.x, a.y), pk2(a.z, a.w), pk2(b.x, b.y), pk2(b.z, b.w));
        *(uint4*)(rawb + tok * 512 + lane * 8) = rp;
    }
    float s = a.x + a.y + a.z + a.w + b.x + b.y + b.z + b.w;
    float q = a.x*a.x + a.y*a.y + a.z*a.z + a.w*a.w + b.x*b.x + b.y*b.y + b.z*b.z + b.w*b.w;
    #pragma unroll
    for (int off = 32; off >= 1; off >>= 1) {
        s += __shfl_xor(s, off);
        q += __shfl_xor(q, off);
    }
    const float m = s * (1.f / 512.f);
    const float v = q * (1.f / 512.f) - m * m;
    const float rs = 1.f / sqrtf(v + 1e-12f);
    float4 gv0 = *(const float4*)(lng + lane * 8);
    float4 gv1 = *(const float4*)(lng + lane * 8 + 4);
    float4 bv0 = *(const float4*)(lnbias + lane * 8);
    float4 bv1 = *(const float4*)(lnbias + lane * 8 + 4);
    float o0 = (a.x - m) * rs * gv0.x + bv0.x;
    float o1 = (a.y - m) * rs * gv0.y + bv0.y;
    float o2 = (a.z - m) * rs * gv0.z + bv0.z;
    float o3 = (a.w - m) * rs * gv0.w + bv0.w;
    float o4 = (b.x - m) * rs * gv1.x + bv1.x;
    float o5 = (b.y - m) * rs * gv1.y + bv1.y;
    float o6 = (b.z - m) * rs * gv1.z + bv1.z;
    float o7 = (b.w - m) * rs * gv1.w + bv1.w;
    uint4 pk = make_uint4(pk2(o0, o1), pk2(o2, o3), pk2(o4, o5), pk2(o6, o7));
    *(uint4*)(outb + tok * 512 + lane * 8) = pk;
}

// ---------- lnpack_h: bf16 input -> LN bf16 out ----------
__global__ void lnpack_h(const ushort_t* __restrict__ xin, const float* __restrict__ lng,
                         const float* __restrict__ lnbias, ushort_t* __restrict__ outb) {
    const int lane = threadIdx.x & 63;
    const int w = threadIdx.x >> 6;
    const size_t tok = (size_t)blockIdx.x * 4 + w;
    const short8* rp = (const short8*)(xin + tok * 512 + lane * 8);
    const short8 r = rp[0];
    float x[8];
    #pragma unroll
    for (int jv = 0; jv < 8; ++jv) x[jv] = bf2f((ushort_t)r[jv]);
    float s = 0.f, q = 0.f;
    #pragma unroll
    for (int jv = 0; jv < 8; ++jv) { s += x[jv]; q += x[jv] * x[jv]; }
    #pragma unroll
    for (int off = 32; off >= 1; off >>= 1) {
        s += __shfl_xor(s, off);
        q += __shfl_xor(q, off);
    }
    const float m = s * (1.f / 512.f);
    const float v = q * (1.f / 512.f) - m * m;
    const float rs = 1.f / sqrtf(v + 1e-12f);
    float4 gv0 = *(const float4*)(lng + lane * 8);
    float4 gv1 = *(const float4*)(lng + lane * 8 + 4);
    float4 bv0 = *(const float4*)(lnbias + lane * 8);
    float4 bv1 = *(const float4*)(lnbias + lane * 8 + 4);
    float o[8];
    o[0] = (x[0] - m) * rs * gv0.x + bv0.x;
    o[1] = (x[1] - m) * rs * gv0.y + bv0.y;
    o[2] = (x[2] - m) * rs * gv0.z + bv0.z;
    o[3] = (x[3] - m) * rs * gv0.w + bv0.w;
    o[4] = (x[4] - m) * rs * gv1.x + bv1.x;
    o[5] = (x[5] - m) * rs * gv1.y + bv1.y;
    o[6] = (x[6] - m) * rs * gv1.z + bv1.z;
    o[7] = (x[7] - m) * rs * gv1.w + bv1.w;
    uint4 pk = make_uint4(pk2(o[0], o[1]), pk2(o[2], o[3]), pk2(o[4], o[5]), pk2(o[6], o[7]));
    *(uint4*)(outb + tok * 512 + lane * 8) = pk;
}

// ---------- fold_w: Weff[1280][512] bf16 = [U.Wq*0.125 | U.Wk | Wv | 0] ----------
// v stays LOW-RANK (round-14: expanding V in the GEMM wasted 17% of the qkv
// GEMM's FLOPs/write; the reference itself does attn@v_low then @V).
__global__ void fold_w(const float* __restrict__ Wq, const float* __restrict__ Wk,
                       const float* __restrict__ Wv, const float* __restrict__ U,
                       ushort_t* __restrict__ Weff) {
    const int o = blockIdx.x;               // 0..1279
    if (o >= 1024) {
        const int rr = o - 1024;            // v_low row (0..127) or pad
        for (int c = threadIdx.x; c < 512; c += 256)
            Weff[(long)o * 512 + c] = (rr < 128) ? f2bf(Wv[rr * 512 + c]) : (ushort_t)0;
        return;
    }
    const int proj = o >> 9, orow = o & 511;
    const int h = orow >> 6, d = orow & 63;
    const float* W = (proj == 0) ? Wq : Wk;
    float coef[16];
    #pragma unroll
    for (int r = 0; r < 16; ++r) coef[r] = U[h * 1024 + d * 16 + r];
    const float scale = (proj == 0) ? 0.125f : 1.f;   // fold 1/sqrt(64) into q
    for (int c = threadIdx.x; c < 512; c += 256) {
        float acc = 0.f;
        #pragma unroll
        for (int r = 0; r < 16; ++r) acc += coef[r] * W[(h * 16 + r) * 512 + c];
        Weff[(long)o * 512 + c] = f2bf(acc * scale);
    }
}

// ---------- gemm_qkv3: qkve[M][1280] = Ab[M][512] @ Weff^T ----------
// 2-phase prefetch gload_lds pipeline + both-sides swizzle (rounds 13/14).
// Grid 8 XCD x 64 panels x 5 col-blocks (cols 1024..1279 = v_low + zero pad).
template<bool TIME>
__launch_bounds__(512)
__global__ void gemm_qkv3(const ushort_t* __restrict__ Ab, const ushort_t* __restrict__ Wb,
                          const float* __restrict__ cosT, const float* __restrict__ sinT,
                          ushort_t* __restrict__ Cout) {
    __shared__ __align__(16) char arena[49152];       // 2 x 24576 (A 8KB + B 16KB)
    ushort_t (*Ebuf)[72] = (ushort_t (*)[72])arena;   // 18432 B (aliases buf0, post-loop)

    const int id = blockIdx.x;            // 0..2559
    const int xcd = id & 7;
    const int j = id >> 3;                // 0..319
    const int mBase = (xcd * 64 + j / 5) * 128;
    const int nBase = (j % 5) * 256;

    const int tid = threadIdx.x;
    const int lane = tid & 63;
    const int w8 = tid >> 6;              // wave 0..7

    f32x4 zero = {0.f, 0.f, 0.f, 0.f};
    f32x4 acc[4][4];
    #pragma unroll
    for (int a = 0; a < 4; ++a)
        #pragma unroll
        for (int b = 0; b < 4; ++b) acc[a][b] = zero;

    const int wr = w8 >> 2, wc = w8 & 3;
    const int l15 = lane & 15;
    const int g = lane >> 4;
    const int arw = wr * 64 + l15;
    const int brw = wc * 64 + l15;

    // per-lane swizzled source addresses for staging
    const int qa = (w8 << 6) + lane;             // A chunk id 0..511
    const int ra = qa >> 2;
    const int ca = (qa & 3) ^ ((ra >> 1) & 3);
    const ushort_t* srcA = Ab + (long)(mBase + ra) * 512 + ca * 8;

    const ushort_t* srcB[2];
    #pragma unroll
    for (int i = 0; i < 2; ++i) {
        const int qb = (w8 << 7) + (i << 6) + lane;   // B chunk id 0..1023
        const int rbv = qb >> 2;
        const int cbv = (qb & 3) ^ ((rbv >> 1) & 3);
        srcB[i] = Wb + (long)(nBase + rbv) * 512 + cbv * 8;
    }

    // prologue: stage kt=0 into buf0
    {
        ushort_t* base = (ushort_t*)arena;
        gload16(srcA, base + (w8 << 9));
        gload16(srcB[0], base + 4096 + (w8 << 10));
        gload16(srcB[1], base + 4096 + (w8 << 10) + 512);
    }
    asm volatile("s_waitcnt vmcnt(0)" ::: "memory");
    __syncthreads();

    #pragma unroll 1
    for (int kt = 0; kt < 512; kt += 32) {
        const int cur = (kt >> 5) & 1;
        // prefetch next tile into the other buffer (flies during MFMA below)
        if (kt + 32 < 512) {
            ushort_t* nb = (ushort_t*)(arena + (cur ^ 1) * 24576);
            gload16(srcA + kt + 32, nb + (w8 << 9));
            gload16(srcB[0] + kt + 32, nb + 4096 + (w8 << 10));
            gload16(srcB[1] + kt + 32, nb + 4096 + (w8 << 10) + 512);
        }
        ushort_t* AsL = (ushort_t*)(arena + cur * 24576);
        ushort_t* BsL = AsL + 4096;

        short8 af[4], bf[4];
        #pragma unroll
        for (int mi = 0; mi < 4; ++mi) {
            const int R = arw + mi * 16;
            af[mi] = *(const short8*)(AsL + R * 32 + ((g ^ ((R >> 1) & 3)) * 8));
        }
        #pragma unroll
        for (int ni = 0; ni < 4; ++ni) {
            const int R = brw + ni * 16;
            bf[ni] = *(const short8*)(BsL + R * 32 + ((g ^ ((R >> 1) & 3)) * 8));
        }
        #pragma unroll
        for (int mi = 0; mi < 4; ++mi)
            #pragma unroll
            for (int ni = 0; ni < 4; ++ni)
                acc[mi][ni] = __builtin_amdgcn_mfma_f32_16x16x32_bf16(af[mi], bf[ni], acc[mi][ni], 0, 0, 0);

        __syncthreads();   // vmcnt/lgkmcnt drain: prefetched loads overlapped MFMA
    }

    // ---- epilogue: 4 stages of 64-col slices through Ebuf (aliases buf0) ----
    #pragma unroll 1
    for (int s = 0; s < 4; ++s) {
        __syncthreads();
        if (wc == s) {
            #pragma unroll
            for (int mi = 0; mi < 4; ++mi)
                #pragma unroll
                for (int ni = 0; ni < 4; ++ni)
                    #pragma unroll
                    for (int jj = 0; jj < 4; ++jj)
                        Ebuf[wr * 64 + mi * 16 + g * 4 + jj][ni * 16 + l15] =
                            f2bf(acc[mi][ni][jj]);
        }
        __syncthreads();
        #pragma unroll
        for (int it = 0; it < 2; ++it) {
            const int u = tid + it * 512;
            const int row = u >> 3, c8 = u & 7;
            short8 v8 = *(const short8*)&Ebuf[row][c8 * 8];
            const long grow = mBase + row;
            const int gcol = nBase + s * 64 + c8 * 8;
            ushort_t* dst = Cout + grow * QKV_W + gcol;
            if (gcol < 1024) {   // rope q_exp / k_exp: pairs are in-lane
                const int pos = TIME ? ((int)(grow >> 8) & 63) : ((int)grow & 255);
                const float* cT = cosT + pos * 32 + c8 * 4;
                const float* sT = sinT + pos * 32 + c8 * 4;
                uint_t pkv[4];
                #pragma unroll
                for (int p = 0; p < 4; ++p) {
                    const float cc = cT[p], ss = sT[p];
                    const float re = bf2f((ushort_t)v8[2 * p]);
                    const float im = bf2f((ushort_t)v8[2 * p + 1]);
                    pkv[p] = pk2(re * cc - im * ss, re * ss + im * cc);
                }
                *(uint4*)dst = make_uint4(pkv[0], pkv[1], pkv[2], pkv[3]);
            } else {             // v_low / pad: straight copy
                *(short8*)dst = v8;
            }
        }
    }
}

// ---------- gemm256: all-bf16 128x256-tile GEMM (gate / proj paths) ----------
template<int EPI>
__launch_bounds__(512)
__global__ void gemm256(const ushort_t* __restrict__ A1b, const ushort_t* __restrict__ A2b,
                        const ushort_t* __restrict__ Bwb, void* __restrict__ Cout_,
                        const float* __restrict__ bias, const ushort_t* __restrict__ R1b,
                        const ushort_t* __restrict__ R2b) {
    constexpr int K = (EPI == 1) ? 1024 : 512;
    __shared__ __align__(16) char arena[49152];

    const int id = blockIdx.x;            // 0..1023
    const int xcd = id & 7;
    const int j = id >> 3;                // 0..127
    const int mBase = (xcd * 64 + (j >> 1)) * 128;
    const int nBase = (j & 1) * 256;

    const int tid = threadIdx.x;
    const int lane = tid & 63;
    const int w8 = tid >> 6;

    f32x4 zero = {0.f, 0.f, 0.f, 0.f};
    f32x4 acc[4][4];
    #pragma unroll
    for (int a = 0; a < 4; ++a)
        #pragma unroll
        for (int b = 0; b < 4; ++b) acc[a][b] = zero;

    const int wr = w8 >> 2, wc = w8 & 3;
    const int l15 = lane & 15;
    const int g = lane >> 4;
    const int arw = wr * 64 + l15;
    const int brw = wc * 64 + l15;

    const int qa = (w8 << 6) + lane;
    const int ra = qa >> 2;
    const int ca = (qa & 3) ^ ((ra >> 1) & 3);
    const long offA = (long)(mBase + ra) * 512 + ca * 8;

    const ushort_t* srcB[2];
    #pragma unroll
    for (int i = 0; i < 2; ++i) {
        const int qb = (w8 << 7) + (i << 6) + lane;
        const int rbv = qb >> 2;
        const int cbv = (qb & 3) ^ ((rbv >> 1) & 3);
        srcB[i] = Bwb + (long)(nBase + rbv) * K + cbv * 8;
    }

    // prologue: stage kt=0 into buf0
    {
        ushort_t* base = (ushort_t*)arena;
        gload16(A1b + offA, base + (w8 << 9));
        gload16(srcB[0], base + 4096 + (w8 << 10));
        gload16(srcB[1], base + 4096 + (w8 << 10) + 512);
    }
    asm volatile("s_waitcnt vmcnt(0)" ::: "memory");
    __syncthreads();

    #pragma unroll 1
    for (int kt = 0; kt < K; kt += 32) {
        const int cur = (kt >> 5) & 1;
        if (kt + 32 < K) {
            const int kn = kt + 32;
            const ushort_t* an = (EPI == 1 && kn >= 512) ? (A2b + offA + (kn - 512))
                                                         : (A1b + offA + kn);
            ushort_t* nb = (ushort_t*)(arena + (cur ^ 1) * 24576);
            gload16(an, nb + (w8 << 9));
            gload16(srcB[0] + kn, nb + 4096 + (w8 << 10));
            gload16(srcB[1] + kn, nb + 4096 + (w8 << 10) + 512);
        }
        ushort_t* AsL = (ushort_t*)(arena + cur * 24576);
        ushort_t* BsL = AsL + 4096;

        short8 af[4], bf[4];
        #pragma unroll
        for (int mi = 0; mi < 4; ++mi) {
            const int R = arw + mi * 16;
            af[mi] = *(const short8*)(AsL + R * 32 + ((g ^ ((R >> 1) & 3)) * 8));
        }
        #pragma unroll
        for (int ni = 0; ni < 4; ++ni) {
            const int R = brw + ni * 16;
            bf[ni] = *(const short8*)(BsL + R * 32 + ((g ^ ((R >> 1) & 3)) * 8));
        }
        #pragma unroll
        for (int mi = 0; mi < 4; ++mi)
            #pragma unroll
            for (int ni = 0; ni < 4; ++ni)
                acc[mi][ni] = __builtin_amdgcn_mfma_f32_16x16x32_bf16(af[mi], bf[ni], acc[mi][ni], 0, 0, 0);

        __syncthreads();
    }

    #pragma unroll
    for (int mi = 0; mi < 4; ++mi) {
        #pragma unroll
        for (int ni = 0; ni < 4; ++ni) {
            #pragma unroll
            for (int jj = 0; jj < 4; ++jj) {
                const long row = mBase + wr * 64 + mi * 16 + ((lane >> 4) << 2) + jj;
                const long col = nBase + wc * 64 + ni * 16 + l15;
                const long idx = row * 512 + col;
                const float v = acc[mi][ni][jj];
                if (EPI == 1) {
                    const float z = v + bias[col];
                    const float gg = 1.f / (1.f + __expf(-z));
                    const float o = gg * bf2f(R1b[idx]) + (1.f - gg) * bf2f(R2b[idx]);
                    ((ushort_t*)Cout_)[idx] = f2bf(o);
                } else {
                    ((float*)Cout_)[idx] = v + bias[col] + bf2f(R1b[idx]);
                }
            }
        }
    }
}

// ---------- attn3: flash MFMA attention, low-rank PV ----------
// qkve[tok][1280] = q_exp|k_exp|v_low. PV runs in rank-16 (O_low = P @ v_low,
// 2 MFMA/chunk instead of 8); final rank->64 expansion per q-tile via one
// transposed A-frag (through the wave-private Pw window, k=16..31 zeroed) x
// VT2 = V^T staged in LDS. Output layout/store identical to before.
template<int SEQ, bool TIME>
__launch_bounds__(256)
__global__ void attn3(const ushort_t* __restrict__ qkve, const float* __restrict__ Vw,
                      ushort_t* __restrict__ xattn) {
    constexpr int NCH = SEQ / 64;
    constexpr int NQT = SEQ / 64;
    constexpr int NPART = 256 / SEQ;
    constexpr int DCH = 8 / NPART;

    __shared__ short Klds[SEQ][64];
    __shared__ short VTs[16][SEQ];    // v_low^T[r][key], swizzled
    __shared__ short Pw[4][16][40];   // per-wave P window / O_low transpose
    __shared__ short VT2[64][40];     // V^T[d][r], cols 16..39 zero (pad: 2-way banks)

    const int bx = blockIdx.x;
    const int h = bx & 7;
    const int grp = bx >> 3;
    int tokBase, tokStride;
    if (TIME) {
        const int l = grp & (L_ - 1);
        const int b = grp >> 8;
        tokBase = b * T_ * L_ + l;
        tokStride = L_;
    } else {
        tokBase = grp * L_;
        tokStride = 1;
    }
    const int tid = threadIdx.x;
    const int lane = tid & 63;
    const int w = tid >> 6;

    // ---- stage VT2 = V[h]^T (fp32 global -> bf16 LDS, zero-padded k) ----
    for (int e = tid; e < 64 * 40; e += 256) {
        const int d = e / 40, r = e % 40;
        VT2[d][r] = (r < 16) ? (short)f2bf(Vw[h * 1024 + r * 64 + d]) : (short)0;
    }

    // ---- stage K (swizzled) and v_low^T (transposed+swizzled) ----
    {
        const int key = tid & (SEQ - 1);
        const int part = tid / SEQ;
        const long tok = tokBase + (long)key * tokStride;
        const ushort_t* kb = qkve + tok * QKV_W + 512 + h * 64;
        const ushort_t* vb = qkve + tok * QKV_W + 1024 + h * 16;
        #pragma unroll
        for (int c = 0; c < DCH; ++c) {
            const int chunk = part * DCH + c;
            const short8 kv = *(const short8*)(kb + chunk * 8);
            *(short8*)&Klds[key][(chunk ^ (key & 7)) * 8] = kv;
        }
        #pragma unroll
        for (int c = part; c < 2; c += NPART) {
            const short8 vv = *(const short8*)(vb + c * 8);
            #pragma unroll
            for (int jx = 0; jx < 8; ++jx) {
                const int d = c * 8 + jx;
                VTs[d][(((key >> 3) ^ (d & 7)) * 8) + (key & 7)] = vv[jx];
            }
        }
    }
    __syncthreads();

    const int l15 = lane & 15;
    const int g = lane >> 4;

    #pragma unroll 1
    for (int qt = 0; qt < NQT; ++qt) {
        const int qbase = qt * 64 + w * 16;
        const long qtok = tokBase + (long)(qbase + l15) * tokStride;

        const ushort_t* qb = qkve + qtok * QKV_W + h * 64;
        const short8 Qf0 = *(const short8*)(qb + g * 8);
        const short8 Qf1 = *(const short8*)(qb + 32 + g * 8);

        f32x4 Olow = {0.f, 0.f, 0.f, 0.f};
        float psum = 0.f;

        #pragma unroll 1
        for (int kb2 = 0; kb2 < NCH; ++kb2) {
            f32x4 S[4];
            #pragma unroll
            for (int f4 = 0; f4 < 4; ++f4) {
                const int row = kb2 * 64 + f4 * 16 + l15;
                const short8 a0 = *(const short8*)&Klds[row][((0 + g) ^ (l15 & 7)) * 8];
                const short8 a1 = *(const short8*)&Klds[row][((4 + g) ^ (l15 & 7)) * 8];
                f32x4 z = {0.f, 0.f, 0.f, 0.f};
                z = __builtin_amdgcn_mfma_f32_16x16x32_bf16(a0, Qf0, z, 0, 0, 0);
                S[f4] = __builtin_amdgcn_mfma_f32_16x16x32_bf16(a1, Qf1, z, 0, 0, 0);
            }
            #pragma unroll
            for (int f4 = 0; f4 < 4; ++f4)
                #pragma unroll
                for (int jj = 0; jj < 4; ++jj) {
                    const float p = __expf(fminf(S[f4][jj], 30.f));
                    S[f4][jj] = p;
                    psum += p;
                }

            // PV in rank space: O_low += P @ v_low (2 MFMA per chunk)
            #pragma unroll
            for (int sl = 0; sl < 2; ++sl) {
                #pragma unroll
                for (int h2 = 0; h2 < 2; ++h2) {
                    const int f4 = 2 * sl + h2;
                    short4v pv;
                    pv[0] = (short)f2bf(S[f4][0]);
                    pv[1] = (short)f2bf(S[f4][1]);
                    pv[2] = (short)f2bf(S[f4][2]);
                    pv[3] = (short)f2bf(S[f4][3]);
                    *(short4v*)&Pw[w][l15][h2 * 16 + 4 * g] = pv;
                }
                const short8 pa = *(const short8*)&Pw[w][l15][8 * g];
                const int sg = kb2 * 2 + sl;
                const short8 bv = *(const short8*)&VTs[l15][((4 * sg + g) ^ (l15 & 7)) * 8];
                Olow = __builtin_amdgcn_mfma_f32_16x16x32_bf16(pa, bv, Olow, 0, 0, 0);
            }
        }

        // normalize, transpose O_low through Pw (k=16..31 zeroed), expand by V^T
        psum += __shfl_xor(psum, 16);
        psum += __shfl_xor(psum, 32);
        const float inv = 1.f / psum;
        #pragma unroll
        for (int jj = 0; jj < 4; ++jj) {
            const float invq = __shfl(inv, 4 * g + jj);
            Pw[w][4 * g + jj][l15] = (short)f2bf(Olow[jj] * invq);
        }
        *(short4v*)&Pw[w][l15][16 + 4 * g] = (short4v){0, 0, 0, 0};
        const short8 pol = *(const short8*)&Pw[w][l15][8 * g];

        f32x4 O[4];
        #pragma unroll
        for (int nj = 0; nj < 4; ++nj) {
            const short8 bvx = *(const short8*)&VT2[nj * 16 + l15][8 * g];
            f32x4 z = {0.f, 0.f, 0.f, 0.f};
            O[nj] = __builtin_amdgcn_mfma_f32_16x16x32_bf16(pol, bvx, z, 0, 0, 0);
        }

        #pragma unroll
        for (int jj = 0; jj < 4; ++jj) {
            const long row = tokBase + (long)(qbase + 4 * g + jj) * tokStride;
            ushort_t* op = xattn + row * 512 + h * 64 + l15;
            #pragma unroll
            for (int nj = 0; nj < 4; ++nj)
                op[nj * 16] = f2bf(O[nj][jj]);
        }
    }
}

// ---------- launch ----------
extern "C" void kernel_launch(void* const* d_in, const int* in_sizes, int n_in,
                              void* d_out, int out_size, void* d_ws, size_t ws_size,
                              hipStream_t stream) {
    const float* x      = (const float*)d_in[0];
    const float* t_Wq   = (const float*)d_in[3];
    const float* t_Wk   = (const float*)d_in[4];
    const float* t_Wv   = (const float*)d_in[5];
    const float* t_U    = (const float*)d_in[6];
    const float* t_V    = (const float*)d_in[7];
    const float* a_Wq   = (const float*)d_in[8];
    const float* a_Wk   = (const float*)d_in[9];
    const float* a_Wv   = (const float*)d_in[10];
    const float* a_U    = (const float*)d_in[11];
    const float* a_V    = (const float*)d_in[12];
    const float* ln1_g  = (const float*)d_in[13];
    const float* ln1_b  = (const float*)d_in[14];
    const float* ln2_g  = (const float*)d_in[15];
    const float* ln2_b  = (const float*)d_in[16];
    const float* ln3_g  = (const float*)d_in[17];
    const float* ln3_b  = (const float*)d_in[18];
    const float* proj_W = (const float*)d_in[19];
    const float* proj_b = (const float*)d_in[20];
    const float* gt_W   = (const float*)d_in[21];
    const float* gt_b   = (const float*)d_in[22];
    const float* ga_W   = (const float*)d_in[23];
    const float* ga_b   = (const float*)d_in[24];
    float* out = (float*)d_out;

    const size_t NC = (size_t)NTOK * 512;
    ushort_t* xb   = (ushort_t*)d_ws;                  // bf16(x), 64MB — dead after gate A
    ushort_t* lnb  = xb + NC;                          // LN out / xatt bf16, 64MB
    ushort_t* resA = lnb + NC;                         // phase-A residual bf16, 64MB
    ushort_t* qkve = resA + NC;                        // q/k/v bf16 [NTOK][1280], 168MB
    ushort_t* resB = qkve;                             // phase-B residual ALIASES qkve
    ushort_t* Weff = qkve + (size_t)NTOK * QKV_W;      // folded attn weights, 1.25MB
    ushort_t* gtWb = Weff + 1280 * 512;                // gate-A weights bf16, 1MB
    ushort_t* gaWb = gtWb + 512 * 1024;                // gate-B weights bf16, 1MB
    ushort_t* prWb = gaWb + 512 * 1024;                // proj weights bf16, 0.5MB
    float* cosT = (float*)(prWb + 512 * 512);
    float* sinT = cosT + 8192;
    ushort_t* xattb = lnb;

    rope_tables<<<32, 256, 0, stream>>>(cosT, sinT);
    packw<<<512, 256, 0, stream>>>(gt_W, gtWb, 512 * 1024);
    packw<<<512, 256, 0, stream>>>(ga_W, gaWb, 512 * 1024);
    packw<<<256, 256, 0, stream>>>(proj_W, prWb, 512 * 512);

    // ===== Phase A: time attention (seq=T, batch=B*L) =====
    fold_w<<<1280, 256, 0, stream>>>(t_Wq, t_Wk, t_Wv, t_U, Weff);
    lnpack_f<true><<<NTOK / 4, 256, 0, stream>>>(x, ln1_g, ln1_b, lnb, xb);
    gemm_qkv3<true><<<2560, 512, 0, stream>>>(lnb, Weff, cosT, sinT, qkve);
    attn3<64, true><<<B_ * L_ * H_, 256, 0, stream>>>(qkve, t_V, xattb);
    gemm256<1><<<1024, 512, 0, stream>>>(xb, xattb, gtWb, resA, gt_b, xb, xattb);

    // ===== Phase B: amino-acid attention (seq=L, batch=B*T) =====
    fold_w<<<1280, 256, 0, stream>>>(a_Wq, a_Wk, a_Wv, a_U, Weff);
    lnpack_h<<<NTOK / 4, 256, 0, stream>>>(resA, ln2_g, ln2_b, lnb);
    gemm_qkv3<false><<<2560, 512, 0, stream>>>(lnb, Weff, cosT, sinT, qkve);
    attn3<256, false><<<B_ * T_ * H_, 256, 0, stream>>>(qkve, a_V, xattb);
    gemm256<1><<<1024, 512, 0, stream>>>(resA, xattb, gaWb, resB, ga_b, resA, xattb);

    // ===== Phase C: output projection + residual =====
    lnpack_h<<<NTOK / 4, 256, 0, stream>>>(resB, ln3_g, ln3_b, lnb);
    gemm256<2><<<1024, 512, 0, stream>>>(lnb, nullptr, prWb, out, proj_b, resB, nullptr);
}